// Round 1
// baseline (2931.115 us; speedup 1.0000x reference)
//
#include <hip/hip_runtime.h>
#include <math.h>

#define D_MODEL 1024
#define DMEM 64
#define CAP 65536
#define SEQ 1024
#define NTOT 2048      // B*S
#define GATE_H 32
#define THETA 0.01f
#define ISQD 0.125f    // 1/sqrt(64)
#define NSPLIT 8
#define CSPL (CAP / NSPLIT)   // 8192
#define FW_NT 32
#define FW_CT 64
#define BW_CT 32
#define BW_NT 64

// ---------------- K1: k = x@Wk+bk, v = x@Wv+bv ----------------
__global__ __launch_bounds__(64) void k_proj(const float* __restrict__ x,
    const float* __restrict__ Wk, const float* __restrict__ bk,
    const float* __restrict__ Wv, const float* __restrict__ bv,
    float* __restrict__ kout, float* __restrict__ vout) {
  __shared__ __align__(16) float xs[D_MODEL];
  int n = blockIdx.x;
  int j = threadIdx.x;
  const float4* xrow = (const float4*)(x + (size_t)n * D_MODEL);
  float4* xs4 = (float4*)xs;
#pragma unroll
  for (int q = 0; q < 4; ++q) xs4[j + 64 * q] = xrow[j + 64 * q];
  __syncthreads();
  float ak = bk[j], av = bv[j];
#pragma unroll 8
  for (int i = 0; i < D_MODEL; ++i) {
    float xv = xs[i];
    ak = fmaf(xv, Wk[i * DMEM + j], ak);
    av = fmaf(xv, Wv[i * DMEM + j], av);
  }
  kout[n * DMEM + j] = ak;
  vout[n * DMEM + j] = av;
}

// ---------------- K2: x_pooled = mean_s x ----------------
__global__ __launch_bounds__(256) void k_pool(const float* __restrict__ x,
                                              float* __restrict__ pooled) {
  int idx = blockIdx.x * 256 + threadIdx.x;   // 0..2047 -> (b, j)
  int b = idx >> 10, j = idx & 1023;
  const float* base = x + (size_t)b * SEQ * D_MODEL + j;
  float s = 0.f;
  for (int t = 0; t < SEQ; ++t) s += base[(size_t)t * D_MODEL];
  pooled[idx] = s * (1.0f / SEQ);
}

// ---------------- K3: gates -> alpha, eta ----------------
__global__ __launch_bounds__(128) void k_gates(const float* __restrict__ pooled,
    const float* __restrict__ fw1, const float* __restrict__ fb1,
    const float* __restrict__ fw2, const float* __restrict__ fb2,
    const float* __restrict__ dw1, const float* __restrict__ db1,
    const float* __restrict__ dw2, const float* __restrict__ db2,
    float* __restrict__ scal) {
  __shared__ float hsh[2][2][GATE_H];
  __shared__ float outs[2][2];
  int t = threadIdx.x;
  int gate = t >> 6, b = (t >> 5) & 1, h = t & 31;
  const float* w1 = gate ? dw1 : fw1;
  const float* b1 = gate ? db1 : fb1;
  float z = b1[h];
  const float* prow = pooled + b * D_MODEL;
  for (int i = 0; i < D_MODEL; ++i) z = fmaf(prow[i], w1[i * GATE_H + h], z);
  float sig = 1.f / (1.f + __expf(-z));
  hsh[gate][b][h] = z * sig;   // silu
  __syncthreads();
  if (t < 4) {
    int gg = t >> 1, bb = t & 1;
    const float* w2 = gg ? dw2 : fw2;
    float zz = gg ? db2[0] : fb2[0];
    for (int hh = 0; hh < GATE_H; ++hh) zz += hsh[gg][bb][hh] * w2[hh];
    outs[gg][bb] = 1.f / (1.f + __expf(-zz));
  }
  __syncthreads();
  if (t == 0) {
    scal[0] = 0.5f * (outs[0][0] + outs[0][1]);  // alpha (forget gate)
    scal[1] = 0.5f * (outs[1][0] + outs[1][1]);  // eta   (decay gate)
  }
}

// ---------------- K4: split-C flash forward ----------------
// grid = (NTOT/FW_NT) * NSPLIT blocks, 256 threads
// thread (tn = tid/8, tc = tid%8): owns n-row tn, d-slice / c-slice index tc
__global__ __launch_bounds__(256) void k_fwd(const float* __restrict__ kmat,
    const float* __restrict__ mem,
    float* __restrict__ m_s, float* __restrict__ l_s, float* __restrict__ r_s) {
  __shared__ __align__(16) float Ml[FW_CT][68];
  int nb = blockIdx.x / NSPLIT, sp = blockIdx.x % NSPLIT;
  int n0 = nb * FW_NT;
  int tid = threadIdx.x;
  int tn = tid >> 3, tc = tid & 7;

  float kreg[64];
  {
    const float4* kr = (const float4*)(kmat + (size_t)(n0 + tn) * DMEM);
#pragma unroll
    for (int q = 0; q < 16; ++q) {
      float4 t4 = kr[q];
      kreg[q * 4 + 0] = t4.x * ISQD;
      kreg[q * 4 + 1] = t4.y * ISQD;
      kreg[q * 4 + 2] = t4.z * ISQD;
      kreg[q * 4 + 3] = t4.w * ISQD;
    }
  }
  float mrun = -1e30f, lrun = 0.f;
  float racc[8];
#pragma unroll
  for (int q = 0; q < 8; ++q) racc[q] = 0.f;

  int c0base = sp * CSPL;
  for (int ct = 0; ct < CSPL / FW_CT; ++ct) {
    int c0 = c0base + ct * FW_CT;
    __syncthreads();   // previous tile's PV reads done before overwrite
    {
      const float4* msrc = (const float4*)(mem + (size_t)c0 * DMEM);
#pragma unroll
      for (int q = 0; q < 4; ++q) {
        int f = tid + 256 * q;
        int row = f >> 4, col = (f & 15) << 2;
        *((float4*)&Ml[row][col]) = msrc[f];
      }
    }
    __syncthreads();
    // scores for (row tn, c = q*8 + tc)
    float sc[8];
#pragma unroll
    for (int q = 0; q < 8; ++q) {
      const float4* mr = (const float4*)&Ml[q * 8 + tc][0];
      float a0 = 0, a1 = 0, a2 = 0, a3 = 0;
#pragma unroll
      for (int i4 = 0; i4 < 16; ++i4) {
        float4 mv = mr[i4];
        a0 = fmaf(kreg[i4 * 4 + 0], mv.x, a0);
        a1 = fmaf(kreg[i4 * 4 + 1], mv.y, a1);
        a2 = fmaf(kreg[i4 * 4 + 2], mv.z, a2);
        a3 = fmaf(kreg[i4 * 4 + 3], mv.w, a3);
      }
      sc[q] = (a0 + a1) + (a2 + a3);
    }
    // online softmax over this tile (row reduce across tc group of 8 lanes)
    float tmax = sc[0];
#pragma unroll
    for (int q = 1; q < 8; ++q) tmax = fmaxf(tmax, sc[q]);
#pragma unroll
    for (int off = 1; off < 8; off <<= 1)
      tmax = fmaxf(tmax, __shfl_xor(tmax, off, 64));
    float mnew = fmaxf(mrun, tmax);
    float scale = __expf(mrun - mnew);
    float tsum = 0.f;
#pragma unroll
    for (int q = 0; q < 8; ++q) { sc[q] = __expf(sc[q] - mnew); tsum += sc[q]; }
#pragma unroll
    for (int off = 1; off < 8; off <<= 1) tsum += __shfl_xor(tsum, off, 64);
    lrun = lrun * scale + tsum;
    mrun = mnew;
#pragma unroll
    for (int q = 0; q < 8; ++q) racc[q] *= scale;
    // PV: racc[dd] += sum_c w[tn][c] * M[c][tc*8+dd]; w fetched via shuffle
#pragma unroll
    for (int q = 0; q < 8; ++q) {
#pragma unroll
      for (int j = 0; j < 8; ++j) {
        int c = q * 8 + j;
        int src = ((tn & 7) << 3) | j;          // lane in this wave holding w[tn][c]
        float wv = __shfl(sc[q], src, 64);
        const float4 m0 = *(const float4*)&Ml[c][tc * 8];
        const float4 m1 = *(const float4*)&Ml[c][tc * 8 + 4];
        racc[0] = fmaf(wv, m0.x, racc[0]);
        racc[1] = fmaf(wv, m0.y, racc[1]);
        racc[2] = fmaf(wv, m0.z, racc[2]);
        racc[3] = fmaf(wv, m0.w, racc[3]);
        racc[4] = fmaf(wv, m1.x, racc[4]);
        racc[5] = fmaf(wv, m1.y, racc[5]);
        racc[6] = fmaf(wv, m1.z, racc[6]);
        racc[7] = fmaf(wv, m1.w, racc[7]);
      }
    }
  }
  int n = n0 + tn;
  if (tc == 0) {
    m_s[sp * NTOT + n] = mrun;
    l_s[sp * NTOT + n] = lrun;
  }
  float* rdst = r_s + ((size_t)sp * NTOT + n) * DMEM + tc * 8;
#pragma unroll
  for (int q = 0; q < 8; ++q) rdst[q] = racc[q];
}

// ---------------- K5: combine splits, loss, g, gdotr ----------------
// grid = NTOT/4 blocks, 256 threads; thread (nl = tid/64, dd = tid%64)
__global__ __launch_bounds__(256) void k_comb(
    const float* __restrict__ m_s, const float* __restrict__ l_s,
    const float* __restrict__ r_s, const float* __restrict__ v,
    float* __restrict__ g, float* __restrict__ gdr8,
    float* __restrict__ mf, float* __restrict__ linv,
    float* __restrict__ lossp) {
  __shared__ float lsum[4];
  int tid = threadIdx.x;
  int nl = tid >> 6, dd = tid & 63;
  int n = blockIdx.x * 4 + nl;
  float m = -1e30f;
#pragma unroll
  for (int s = 0; s < NSPLIT; ++s) m = fmaxf(m, m_s[s * NTOT + n]);
  float l = 0.f;
  float esc[NSPLIT];
#pragma unroll
  for (int s = 0; s < NSPLIT; ++s) {
    esc[s] = __expf(m_s[s * NTOT + n] - m);
    l += esc[s] * l_s[s * NTOT + n];
  }
  float r = 0.f;
#pragma unroll
  for (int s = 0; s < NSPLIT; ++s)
    r += esc[s] * r_s[((size_t)s * NTOT + n) * DMEM + dd];
  float li = 1.f / l;
  float ret = r * li;
  float vv = v[n * DMEM + dd];
  const float c0 = 2.f / (float)(NTOT * DMEM);
  float diff = ret - vv;
  float gv = c0 * diff;
  g[n * DMEM + dd] = gv;
  float gr = gv * ret;
  float lp = diff * diff;
#pragma unroll
  for (int off = 1; off < 64; off <<= 1) {
    gr += __shfl_xor(gr, off, 64);
    lp += __shfl_xor(lp, off, 64);
  }
  if (dd == 0) {
    gdr8[n] = gr * ISQD;   // (g . retrieved)/sqrt(d)
    mf[n] = m;
    linv[n] = li;
    lsum[nl] = lp;
  }
  __syncthreads();
  if (tid == 0)
    lossp[blockIdx.x] =
        (lsum[0] + lsum[1] + lsum[2] + lsum[3]) * (1.f / (float)(NTOT * DMEM));
}

// ---------------- K6: backward (c-stationary) ----------------
// grid = CAP/BW_CT blocks, 256 threads; thread (cr = tid/8, dp = tid%8)
__global__ __launch_bounds__(256) void k_bwd(
    const float* __restrict__ kmat, const float* __restrict__ mem,
    const float* __restrict__ g, const float* __restrict__ gdr8,
    const float* __restrict__ mf, const float* __restrict__ linv,
    float* __restrict__ grad, float* __restrict__ gnsqp) {
  __shared__ __align__(16) float kt[BW_NT][68];
  __shared__ __align__(16) float gt[BW_NT][68];
  __shared__ float mt[BW_NT], lit[BW_NT], gdt[BW_NT];
  __shared__ float red[4];
  int tid = threadIdx.x;
  int cr = tid >> 3, dp = tid & 7;
  int c = blockIdx.x * BW_CT + cr;
  float Mreg[8];
  {
    const float4* mr = (const float4*)(mem + (size_t)c * DMEM + dp * 8);
    float4 a = mr[0], b = mr[1];
    Mreg[0] = a.x * ISQD; Mreg[1] = a.y * ISQD; Mreg[2] = a.z * ISQD; Mreg[3] = a.w * ISQD;
    Mreg[4] = b.x * ISQD; Mreg[5] = b.y * ISQD; Mreg[6] = b.z * ISQD; Mreg[7] = b.w * ISQD;
  }
  float acc[8];
#pragma unroll
  for (int q = 0; q < 8; ++q) acc[q] = 0.f;

  for (int nt = 0; nt < NTOT / BW_NT; ++nt) {
    int n0 = nt * BW_NT;
    __syncthreads();
    {
      const float4* ks = (const float4*)(kmat + (size_t)n0 * DMEM);
      const float4* gs = (const float4*)(g + (size_t)n0 * DMEM);
#pragma unroll
      for (int q = 0; q < 4; ++q) {
        int f = tid + 256 * q;
        int row = f >> 4, col = (f & 15) << 2;
        *(float4*)&kt[row][col] = ks[f];
        *(float4*)&gt[row][col] = gs[f];
      }
      if (tid < BW_NT) {
        mt[tid] = mf[n0 + tid];
        lit[tid] = linv[n0 + tid];
        gdt[tid] = gdr8[n0 + tid];
      }
    }
    __syncthreads();
    for (int nn = 0; nn < BW_NT; ++nn) {
      const float4 k0 = *(const float4*)&kt[nn][dp * 8];
      const float4 k1 = *(const float4*)&kt[nn][dp * 8 + 4];
      const float4 g0 = *(const float4*)&gt[nn][dp * 8];
      const float4 g1 = *(const float4*)&gt[nn][dp * 8 + 4];
      float ps = k0.x * Mreg[0] + k0.y * Mreg[1] + k0.z * Mreg[2] + k0.w * Mreg[3] +
                 k1.x * Mreg[4] + k1.y * Mreg[5] + k1.z * Mreg[6] + k1.w * Mreg[7];
      float pg = g0.x * Mreg[0] + g0.y * Mreg[1] + g0.z * Mreg[2] + g0.w * Mreg[3] +
                 g1.x * Mreg[4] + g1.y * Mreg[5] + g1.z * Mreg[6] + g1.w * Mreg[7];
#pragma unroll
      for (int off = 1; off < 8; off <<= 1) {
        ps += __shfl_xor(ps, off, 64);
        pg += __shfl_xor(pg, off, 64);
      }
      float w = __expf(ps - mt[nn]) * lit[nn];
      float wc = w * (pg - gdt[nn]);
      acc[0] = fmaf(w, g0.x, fmaf(wc, k0.x, acc[0]));
      acc[1] = fmaf(w, g0.y, fmaf(wc, k0.y, acc[1]));
      acc[2] = fmaf(w, g0.z, fmaf(wc, k0.z, acc[2]));
      acc[3] = fmaf(w, g0.w, fmaf(wc, k0.w, acc[3]));
      acc[4] = fmaf(w, g1.x, fmaf(wc, k1.x, acc[4]));
      acc[5] = fmaf(w, g1.y, fmaf(wc, k1.y, acc[5]));
      acc[6] = fmaf(w, g1.z, fmaf(wc, k1.z, acc[6]));
      acc[7] = fmaf(w, g1.w, fmaf(wc, k1.w, acc[7]));
    }
  }
  float* gd = grad + (size_t)c * DMEM + dp * 8;
  float ss = 0.f;
#pragma unroll
  for (int q = 0; q < 8; ++q) { gd[q] = acc[q]; ss = fmaf(acc[q], acc[q], ss); }
#pragma unroll
  for (int off = 1; off < 64; off <<= 1) ss += __shfl_xor(ss, off, 64);
  if ((tid & 63) == 0) red[tid >> 6] = ss;
  __syncthreads();
  if (tid == 0) gnsqp[blockIdx.x] = red[0] + red[1] + red[2] + red[3];
}

// ---------------- K7: final scalar reduce (grad norm, loss) ----------------
__global__ __launch_bounds__(256) void k_fin(const float* __restrict__ gnsqp,
                                             const float* __restrict__ lossp,
                                             float* __restrict__ scal) {
  __shared__ float sh[8];
  int tid = threadIdx.x;
  float s1 = 0.f, s2 = 0.f;
  for (int i = tid; i < CAP / BW_CT; i += 256) s1 += gnsqp[i];
  for (int i = tid; i < NTOT / 4; i += 256) s2 += lossp[i];
#pragma unroll
  for (int off = 1; off < 64; off <<= 1) {
    s1 += __shfl_xor(s1, off, 64);
    s2 += __shfl_xor(s2, off, 64);
  }
  if ((tid & 63) == 0) { sh[(tid >> 6) * 2] = s1; sh[(tid >> 6) * 2 + 1] = s2; }
  __syncthreads();
  if (tid == 0) {
    float gnsq = sh[0] + sh[2] + sh[4] + sh[6];
    float loss = sh[1] + sh[3] + sh[5] + sh[7];
    float gn = sqrtf(gnsq);
    float clip = (gn > 1.0f) ? (1.0f / gn) : 1.0f;   // min(1, 1/gn)
    scal[2] = THETA * clip;
    scal[3] = loss;
  }
}

// ---------------- K8: M_new / S_new / loss write ----------------
__global__ __launch_bounds__(256) void k_upd(const float* __restrict__ mem,
    const float* __restrict__ momS, const float* __restrict__ grad,
    const float* __restrict__ scal, float* __restrict__ dout) {
  size_t i = (size_t)blockIdx.x * 256 + threadIdx.x;
  float oma = 1.f - scal[0];
  float eta = scal[1];
  float th = scal[2];
  if (i == 0) dout[0] = scal[3];
  float gr = grad[i];
  float sn = fmaf(-th, gr, eta * momS[i]);
  dout[1 + (size_t)CAP * DMEM + i] = sn;       // S_new (overwrites grad scratch)
  dout[1 + i] = fmaf(oma, mem[i], sn);         // M_new
}

extern "C" void kernel_launch(void* const* d_in, const int* in_sizes, int n_in,
                              void* d_out, int out_size, void* d_ws, size_t ws_size,
                              hipStream_t stream) {
  const float* x    = (const float*)d_in[0];
  const float* mem  = (const float*)d_in[1];
  const float* momS = (const float*)d_in[2];
  const float* Wk   = (const float*)d_in[3];
  const float* bk   = (const float*)d_in[4];
  const float* Wv   = (const float*)d_in[5];
  const float* bv   = (const float*)d_in[6];
  const float* fw1  = (const float*)d_in[7];
  const float* fb1  = (const float*)d_in[8];
  const float* fw2  = (const float*)d_in[9];
  const float* fb2  = (const float*)d_in[10];
  const float* dw1  = (const float*)d_in[11];
  const float* db1  = (const float*)d_in[12];
  const float* dw2  = (const float*)d_in[13];
  const float* db2  = (const float*)d_in[14];

  float* out = (float*)d_out;
  float* wsf = (float*)d_ws;

  // small scratch in ws (~1.7 MB)
  float* scal   = wsf;                    // 16
  float* pooled = wsf + 16;               // 2048
  float* kbuf   = wsf + 2064;             // 131072
  float* vbuf   = kbuf + 131072;          // 131072
  float* gbuf   = vbuf + 131072;          // 131072
  float* gdr8   = gbuf + 131072;          // 2048
  float* mfb    = gdr8 + 2048;            // 2048
  float* linvb  = mfb + 2048;             // 2048
  float* msb    = linvb + 2048;           // NSPLIT*NTOT = 16384
  float* lsb    = msb + 16384;            // 16384
  float* lossp  = lsb + 16384;            // 512
  float* gnsqp  = lossp + 512;            // 2048

  // big scratch parked inside d_out (dead until k_upd overwrites it)
  float* rsb  = out + 1;                          // split r: 8*2048*64 = 1,048,576 <= 4,194,304
  float* grad = out + 1 + (size_t)CAP * DMEM;     // grad_M in S_new slot

  k_proj <<<NTOT, 64, 0, stream>>>(x, Wk, bk, Wv, bv, kbuf, vbuf);
  k_pool <<<8, 256, 0, stream>>>(x, pooled);
  k_gates<<<1, 128, 0, stream>>>(pooled, fw1, fb1, fw2, fb2, dw1, db1, dw2, db2, scal);
  k_fwd  <<<(NTOT / FW_NT) * NSPLIT, 256, 0, stream>>>(kbuf, mem, msb, lsb, rsb);
  k_comb <<<NTOT / 4, 256, 0, stream>>>(msb, lsb, rsb, vbuf, gbuf, gdr8, mfb, linvb, lossp);
  k_bwd  <<<CAP / BW_CT, 256, 0, stream>>>(kbuf, mem, gbuf, gdr8, mfb, linvb, grad, gnsqp);
  k_fin  <<<1, 256, 0, stream>>>(gnsqp, lossp, scal);
  k_upd  <<<(CAP * DMEM) / 256, 256, 0, stream>>>(mem, momS, grad, scal, out);
}

// Round 2
// 1639.204 us; speedup vs baseline: 1.7881x; 1.7881x over previous
//
#include <hip/hip_runtime.h>
#include <math.h>

#define D_MODEL 1024
#define DMEM 64
#define CAP 65536
#define SEQ 1024
#define NTOT 2048      // B*S
#define GATE_H 32
#define THETA 0.01f
#define ISQD 0.125f    // 1/sqrt(64)
#define NSPLIT 8
#define CSPL (CAP / NSPLIT)   // 8192
#define FW_NT 32
#define FW_CT 64
#define GN_BLOCKS (CAP / 64)  // 1024

typedef float f32x4 __attribute__((ext_vector_type(4)));
typedef short bf16x8 __attribute__((ext_vector_type(8)));
typedef unsigned int u32x4 __attribute__((ext_vector_type(4)));

#define MFMA16(a, b, c) __builtin_amdgcn_mfma_f32_16x16x32_bf16(a, b, c, 0, 0, 0)

__device__ inline unsigned short f2bf(float f) {
  union { float f; unsigned u; } v; v.f = f;
  unsigned r = v.u + 0x7FFFu + ((v.u >> 16) & 1u);
  return (unsigned short)(r >> 16);
}
__device__ inline unsigned pk2(float a, float b) {
  return (unsigned)f2bf(a) | ((unsigned)f2bf(b) << 16);
}

// ---------------- K0: Msb = bf16(mem * 0.125) ----------------
__global__ __launch_bounds__(256) void k_packm(const float* __restrict__ mem,
                                               unsigned short* __restrict__ Msb) {
  size_t i = ((size_t)blockIdx.x * 256 + threadIdx.x) * 8;
  float4 a = *(const float4*)(mem + i);
  float4 b = *(const float4*)(mem + i + 4);
  union { unsigned short s[8]; u32x4 v; } o;
  o.s[0] = f2bf(a.x * ISQD); o.s[1] = f2bf(a.y * ISQD);
  o.s[2] = f2bf(a.z * ISQD); o.s[3] = f2bf(a.w * ISQD);
  o.s[4] = f2bf(b.x * ISQD); o.s[5] = f2bf(b.y * ISQD);
  o.s[6] = f2bf(b.z * ISQD); o.s[7] = f2bf(b.w * ISQD);
  *(u32x4*)(Msb + i) = o.v;
}

// ---------------- K1: k = x@Wk+bk, v = x@Wv+bv (+bf16 copies of k) ----------------
__global__ __launch_bounds__(64) void k_proj(const float* __restrict__ x,
    const float* __restrict__ Wk, const float* __restrict__ bk,
    const float* __restrict__ Wv, const float* __restrict__ bv,
    float* __restrict__ kout, float* __restrict__ vout,
    unsigned short* __restrict__ kb, unsigned short* __restrict__ kbT) {
  __shared__ __align__(16) float xs[D_MODEL];
  int n = blockIdx.x;
  int j = threadIdx.x;
  const float4* xrow = (const float4*)(x + (size_t)n * D_MODEL);
  float4* xs4 = (float4*)xs;
#pragma unroll
  for (int q = 0; q < 4; ++q) xs4[j + 64 * q] = xrow[j + 64 * q];
  __syncthreads();
  float ak = bk[j], av = bv[j];
#pragma unroll 8
  for (int i = 0; i < D_MODEL; ++i) {
    float xv = xs[i];
    ak = fmaf(xv, Wk[i * DMEM + j], ak);
    av = fmaf(xv, Wv[i * DMEM + j], av);
  }
  kout[n * DMEM + j] = ak;
  vout[n * DMEM + j] = av;
  kb[n * DMEM + j] = f2bf(ak);
  kbT[j * NTOT + n] = f2bf(ak);
}

// ---------------- K2: x_pooled = mean_s x ----------------
__global__ __launch_bounds__(256) void k_pool(const float* __restrict__ x,
                                              float* __restrict__ pooled) {
  int idx = blockIdx.x * 256 + threadIdx.x;
  int b = idx >> 10, j = idx & 1023;
  const float* base = x + (size_t)b * SEQ * D_MODEL + j;
  float s = 0.f;
  for (int t = 0; t < SEQ; ++t) s += base[(size_t)t * D_MODEL];
  pooled[idx] = s * (1.0f / SEQ);
}

// ---------------- K3: gates -> alpha, eta ----------------
__global__ __launch_bounds__(128) void k_gates(const float* __restrict__ pooled,
    const float* __restrict__ fw1, const float* __restrict__ fb1,
    const float* __restrict__ fw2, const float* __restrict__ fb2,
    const float* __restrict__ dw1, const float* __restrict__ db1,
    const float* __restrict__ dw2, const float* __restrict__ db2,
    float* __restrict__ scal) {
  __shared__ float hsh[2][2][GATE_H];
  __shared__ float outs[2][2];
  int t = threadIdx.x;
  int gate = t >> 6, b = (t >> 5) & 1, h = t & 31;
  const float* w1 = gate ? dw1 : fw1;
  const float* b1 = gate ? db1 : fb1;
  float z = b1[h];
  const float* prow = pooled + b * D_MODEL;
  for (int i = 0; i < D_MODEL; ++i) z = fmaf(prow[i], w1[i * GATE_H + h], z);
  float sig = 1.f / (1.f + __expf(-z));
  hsh[gate][b][h] = z * sig;
  __syncthreads();
  if (t < 4) {
    int gg = t >> 1, bb = t & 1;
    const float* w2 = gg ? dw2 : fw2;
    float zz = gg ? db2[0] : fb2[0];
    for (int hh = 0; hh < GATE_H; ++hh) zz += hsh[gg][bb][hh] * w2[hh];
    outs[gg][bb] = 1.f / (1.f + __expf(-zz));
  }
  __syncthreads();
  if (t == 0) {
    scal[0] = 0.5f * (outs[0][0] + outs[0][1]);  // alpha
    scal[1] = 0.5f * (outs[1][0] + outs[1][1]);  // eta
  }
}

// ---------------- K4: split-C flash forward (f32) ----------------
__global__ __launch_bounds__(256) void k_fwd(const float* __restrict__ kmat,
    const float* __restrict__ mem,
    float* __restrict__ m_s, float* __restrict__ l_s, float* __restrict__ r_s) {
  __shared__ __align__(16) float Ml[FW_CT][68];
  int nb = blockIdx.x / NSPLIT, sp = blockIdx.x % NSPLIT;
  int n0 = nb * FW_NT;
  int tid = threadIdx.x;
  int tn = tid >> 3, tc = tid & 7;

  float kreg[64];
  {
    const float4* kr = (const float4*)(kmat + (size_t)(n0 + tn) * DMEM);
#pragma unroll
    for (int q = 0; q < 16; ++q) {
      float4 t4 = kr[q];
      kreg[q * 4 + 0] = t4.x * ISQD;
      kreg[q * 4 + 1] = t4.y * ISQD;
      kreg[q * 4 + 2] = t4.z * ISQD;
      kreg[q * 4 + 3] = t4.w * ISQD;
    }
  }
  float mrun = -1e30f, lrun = 0.f;
  float racc[8];
#pragma unroll
  for (int q = 0; q < 8; ++q) racc[q] = 0.f;

  int c0base = sp * CSPL;
  for (int ct = 0; ct < CSPL / FW_CT; ++ct) {
    int c0 = c0base + ct * FW_CT;
    __syncthreads();
    {
      const float4* msrc = (const float4*)(mem + (size_t)c0 * DMEM);
#pragma unroll
      for (int q = 0; q < 4; ++q) {
        int f = tid + 256 * q;
        int row = f >> 4, col = (f & 15) << 2;
        *((float4*)&Ml[row][col]) = msrc[f];
      }
    }
    __syncthreads();
    float sc[8];
#pragma unroll
    for (int q = 0; q < 8; ++q) {
      const float4* mr = (const float4*)&Ml[q * 8 + tc][0];
      float a0 = 0, a1 = 0, a2 = 0, a3 = 0;
#pragma unroll
      for (int i4 = 0; i4 < 16; ++i4) {
        float4 mv = mr[i4];
        a0 = fmaf(kreg[i4 * 4 + 0], mv.x, a0);
        a1 = fmaf(kreg[i4 * 4 + 1], mv.y, a1);
        a2 = fmaf(kreg[i4 * 4 + 2], mv.z, a2);
        a3 = fmaf(kreg[i4 * 4 + 3], mv.w, a3);
      }
      sc[q] = (a0 + a1) + (a2 + a3);
    }
    float tmax = sc[0];
#pragma unroll
    for (int q = 1; q < 8; ++q) tmax = fmaxf(tmax, sc[q]);
#pragma unroll
    for (int off = 1; off < 8; off <<= 1)
      tmax = fmaxf(tmax, __shfl_xor(tmax, off, 64));
    float mnew = fmaxf(mrun, tmax);
    float scale = __expf(mrun - mnew);
    float tsum = 0.f;
#pragma unroll
    for (int q = 0; q < 8; ++q) { sc[q] = __expf(sc[q] - mnew); tsum += sc[q]; }
#pragma unroll
    for (int off = 1; off < 8; off <<= 1) tsum += __shfl_xor(tsum, off, 64);
    lrun = lrun * scale + tsum;
    mrun = mnew;
#pragma unroll
    for (int q = 0; q < 8; ++q) racc[q] *= scale;
#pragma unroll
    for (int q = 0; q < 8; ++q) {
#pragma unroll
      for (int j = 0; j < 8; ++j) {
        int c = q * 8 + j;
        int src = ((tn & 7) << 3) | j;
        float wv = __shfl(sc[q], src, 64);
        const float4 m0 = *(const float4*)&Ml[c][tc * 8];
        const float4 m1 = *(const float4*)&Ml[c][tc * 8 + 4];
        racc[0] = fmaf(wv, m0.x, racc[0]);
        racc[1] = fmaf(wv, m0.y, racc[1]);
        racc[2] = fmaf(wv, m0.z, racc[2]);
        racc[3] = fmaf(wv, m0.w, racc[3]);
        racc[4] = fmaf(wv, m1.x, racc[4]);
        racc[5] = fmaf(wv, m1.y, racc[5]);
        racc[6] = fmaf(wv, m1.z, racc[6]);
        racc[7] = fmaf(wv, m1.w, racc[7]);
      }
    }
  }
  int n = n0 + tn;
  if (tc == 0) {
    m_s[sp * NTOT + n] = mrun;
    l_s[sp * NTOT + n] = lrun;
  }
  float* rdst = r_s + ((size_t)sp * NTOT + n) * DMEM + tc * 8;
#pragma unroll
  for (int q = 0; q < 8; ++q) rdst[q] = racc[q];
}

// ---------------- K5: combine splits, loss, g (bf16 out), gdotr ----------------
__global__ __launch_bounds__(256) void k_comb(
    const float* __restrict__ m_s, const float* __restrict__ l_s,
    const float* __restrict__ r_s, const float* __restrict__ v,
    unsigned short* __restrict__ gb, unsigned short* __restrict__ gbT,
    float* __restrict__ gdr8, float* __restrict__ mf, float* __restrict__ linv,
    float* __restrict__ lossp) {
  __shared__ float lsum[4];
  int tid = threadIdx.x;
  int nl = tid >> 6, dd = tid & 63;
  int n = blockIdx.x * 4 + nl;
  float m = -1e30f;
#pragma unroll
  for (int s = 0; s < NSPLIT; ++s) m = fmaxf(m, m_s[s * NTOT + n]);
  float l = 0.f;
  float esc[NSPLIT];
#pragma unroll
  for (int s = 0; s < NSPLIT; ++s) {
    esc[s] = __expf(m_s[s * NTOT + n] - m);
    l += esc[s] * l_s[s * NTOT + n];
  }
  float r = 0.f;
#pragma unroll
  for (int s = 0; s < NSPLIT; ++s)
    r += esc[s] * r_s[((size_t)s * NTOT + n) * DMEM + dd];
  float li = 1.f / l;
  float ret = r * li;
  float vv = v[n * DMEM + dd];
  const float c0 = 2.f / (float)(NTOT * DMEM);
  float diff = ret - vv;
  float gv = c0 * diff;
  gb[n * DMEM + dd] = f2bf(gv);
  gbT[dd * NTOT + n] = f2bf(gv);
  float gr = gv * ret;
  float lp = diff * diff;
#pragma unroll
  for (int off = 1; off < 64; off <<= 1) {
    gr += __shfl_xor(gr, off, 64);
    lp += __shfl_xor(lp, off, 64);
  }
  if (dd == 0) {
    gdr8[n] = gr * ISQD;
    mf[n] = m;
    linv[n] = li;
    lsum[nl] = lp;
  }
  __syncthreads();
  if (tid == 0)
    lossp[blockIdx.x] =
        (lsum[0] + lsum[1] + lsum[2] + lsum[3]) * (1.f / (float)(NTOT * DMEM));
}

// ---------------- K6: MFMA backward ----------------
// grid = CAP/64 blocks, 256 threads = 4 waves; wave owns 16 c-rows.
// Per n-step(32): S[n,c], pg[n,c] via MFMA; w/coef -> per-wave LDS tile [c][n];
// grad[c,d] += mfma(w, G[n,d]) + mfma(coef, K[n,d])  (B from gbT/kbT [d][n]).
__global__ __launch_bounds__(256, 3) void k_bwd2(
    const unsigned short* __restrict__ kb, const unsigned short* __restrict__ kbT,
    const unsigned short* __restrict__ gb, const unsigned short* __restrict__ gbT,
    const unsigned short* __restrict__ Msb,
    const float* __restrict__ mf, const float* __restrict__ linv,
    const float* __restrict__ gdr8,
    float* __restrict__ grad, float* __restrict__ gnsqp) {
  // per-wave tiles: [c=16][n=32 bf16] pitch 40 shorts (80B) -> 20 uints
  __shared__ unsigned wt[4][16 * 20];
  __shared__ unsigned ct[4][16 * 20];
  __shared__ float red[4];
  int tid = threadIdx.x;
  int wv = tid >> 6, lane = tid & 63;
  int u = lane >> 4, p = lane & 15;
  int cw = blockIdx.x * 64 + wv * 16;

  // persistent M fragments (B operand): lane -> col c'=p, k=d = kk*32 + u*8 + j
  bf16x8 bM0 = *(const bf16x8*)(Msb + (size_t)(cw + p) * DMEM + u * 8);
  bf16x8 bM1 = *(const bf16x8*)(Msb + (size_t)(cw + p) * DMEM + 32 + u * 8);

  f32x4 gacc[4];
#pragma unroll
  for (int q = 0; q < 4; ++q) gacc[q] = (f32x4){0.f, 0.f, 0.f, 0.f};

  for (int nt = 0; nt < NTOT / 32; ++nt) {
    int n0 = nt * 32;
    // A fragments: row n = n0 + nf*16 + p, k = d
    const unsigned short* kbase = kb + (size_t)(n0 + p) * DMEM + u * 8;
    const unsigned short* gbase = gb + (size_t)(n0 + p) * DMEM + u * 8;
    bf16x8 ak00 = *(const bf16x8*)(kbase);
    bf16x8 ak01 = *(const bf16x8*)(kbase + 32);
    bf16x8 ak10 = *(const bf16x8*)(kbase + 16 * DMEM);
    bf16x8 ak11 = *(const bf16x8*)(kbase + 16 * DMEM + 32);
    bf16x8 ag00 = *(const bf16x8*)(gbase);
    bf16x8 ag01 = *(const bf16x8*)(gbase + 32);
    bf16x8 ag10 = *(const bf16x8*)(gbase + 16 * DMEM);
    bf16x8 ag11 = *(const bf16x8*)(gbase + 16 * DMEM + 32);

    f32x4 s0 = (f32x4){0.f, 0.f, 0.f, 0.f}, s1 = s0, pg0 = s0, pg1 = s0;
    s0 = MFMA16(ak00, bM0, s0);  s0 = MFMA16(ak01, bM1, s0);
    s1 = MFMA16(ak10, bM0, s1);  s1 = MFMA16(ak11, bM1, s1);
    pg0 = MFMA16(ag00, bM0, pg0); pg0 = MFMA16(ag01, bM1, pg0);
    pg1 = MFMA16(ag10, bM0, pg1); pg1 = MFMA16(ag11, bM1, pg1);

    // per-lane scalars for rows n = n0 + nf*16 + 4u + r
    float4 m0 = *(const float4*)(mf + n0 + u * 4);
    float4 m1 = *(const float4*)(mf + n0 + 16 + u * 4);
    float4 l0 = *(const float4*)(linv + n0 + u * 4);
    float4 l1 = *(const float4*)(linv + n0 + 16 + u * 4);
    float4 d0 = *(const float4*)(gdr8 + n0 + u * 4);
    float4 d1 = *(const float4*)(gdr8 + n0 + 16 + u * 4);

    float w00 = __expf(s0.x - m0.x) * l0.x;
    float w01 = __expf(s0.y - m0.y) * l0.y;
    float w02 = __expf(s0.z - m0.z) * l0.z;
    float w03 = __expf(s0.w - m0.w) * l0.w;
    float w10 = __expf(s1.x - m1.x) * l1.x;
    float w11 = __expf(s1.y - m1.y) * l1.y;
    float w12 = __expf(s1.z - m1.z) * l1.z;
    float w13 = __expf(s1.w - m1.w) * l1.w;
    float c00 = w00 * (pg0.x - d0.x);
    float c01 = w01 * (pg0.y - d0.y);
    float c02 = w02 * (pg0.z - d0.z);
    float c03 = w03 * (pg0.w - d0.w);
    float c10 = w10 * (pg1.x - d1.x);
    float c11 = w11 * (pg1.y - d1.y);
    float c12 = w12 * (pg1.z - d1.z);
    float c13 = w13 * (pg1.w - d1.w);

    asm volatile("" ::: "memory");
    // tile write: [c=p][n_local = nf*16 + 4u + {0..3}] packed as 2 bf16/uint
    unsigned* wr = &wt[wv][p * 20];
    unsigned* cr = &ct[wv][p * 20];
    wr[2 * u + 0] = pk2(w00, w01);
    wr[2 * u + 1] = pk2(w02, w03);
    wr[8 + 2 * u + 0] = pk2(w10, w11);
    wr[8 + 2 * u + 1] = pk2(w12, w13);
    cr[2 * u + 0] = pk2(c00, c01);
    cr[2 * u + 1] = pk2(c02, c03);
    cr[8 + 2 * u + 0] = pk2(c10, c11);
    cr[8 + 2 * u + 1] = pk2(c12, c13);
    __syncthreads();
    // A-frag read: row c'=p, k=n = u*8+j
    u32x4 aw4 = *(const u32x4*)&wt[wv][p * 20 + u * 4];
    u32x4 ac4 = *(const u32x4*)&ct[wv][p * 20 + u * 4];
    asm volatile("" ::: "memory");
    bf16x8 aw = __builtin_bit_cast(bf16x8, aw4);
    bf16x8 ac = __builtin_bit_cast(bf16x8, ac4);
#pragma unroll
    for (int df = 0; df < 4; ++df) {
      bf16x8 bg = *(const bf16x8*)(gbT + (size_t)(df * 16 + p) * NTOT + n0 + u * 8);
      bf16x8 bk2 = *(const bf16x8*)(kbT + (size_t)(df * 16 + p) * NTOT + n0 + u * 8);
      gacc[df] = MFMA16(aw, bg, gacc[df]);
      gacc[df] = MFMA16(ac, bk2, gacc[df]);
    }
  }

  // write grad + norm partial; D layout: row c = cw + 4u + r, col d = df*16 + p
  float ss = 0.f;
#pragma unroll
  for (int df = 0; df < 4; ++df) {
#pragma unroll
    for (int r = 0; r < 4; ++r) {
      float gv = gacc[df][r];
      grad[(size_t)(cw + 4 * u + r) * DMEM + df * 16 + p] = gv;
      ss = fmaf(gv, gv, ss);
    }
  }
#pragma unroll
  for (int off = 1; off < 64; off <<= 1) ss += __shfl_xor(ss, off, 64);
  if (lane == 0) red[wv] = ss;
  __syncthreads();
  if (tid == 0) gnsqp[blockIdx.x] = red[0] + red[1] + red[2] + red[3];
}

// ---------------- K7: final scalar reduce ----------------
__global__ __launch_bounds__(256) void k_fin(const float* __restrict__ gnsqp,
                                             const float* __restrict__ lossp,
                                             float* __restrict__ scal) {
  __shared__ float sh[8];
  int tid = threadIdx.x;
  float s1 = 0.f, s2 = 0.f;
  for (int i = tid; i < GN_BLOCKS; i += 256) s1 += gnsqp[i];
  for (int i = tid; i < NTOT / 4; i += 256) s2 += lossp[i];
#pragma unroll
  for (int off = 1; off < 64; off <<= 1) {
    s1 += __shfl_xor(s1, off, 64);
    s2 += __shfl_xor(s2, off, 64);
  }
  if ((tid & 63) == 0) { sh[(tid >> 6) * 2] = s1; sh[(tid >> 6) * 2 + 1] = s2; }
  __syncthreads();
  if (tid == 0) {
    float gnsq = sh[0] + sh[2] + sh[4] + sh[6];
    float loss = sh[1] + sh[3] + sh[5] + sh[7];
    float gn = sqrtf(gnsq);
    float clip = (gn > 1.0f) ? (1.0f / gn) : 1.0f;
    scal[2] = THETA * clip;
    scal[3] = loss;
  }
}

// ---------------- K8: M_new / S_new / loss write ----------------
__global__ __launch_bounds__(256) void k_upd(const float* __restrict__ mem,
    const float* __restrict__ momS, const float* __restrict__ grad,
    const float* __restrict__ scal, float* __restrict__ dout) {
  size_t i = (size_t)blockIdx.x * 256 + threadIdx.x;
  float oma = 1.f - scal[0];
  float eta = scal[1];
  float th = scal[2];
  if (i == 0) dout[0] = scal[3];
  float gr = grad[i];
  float sn = fmaf(-th, gr, eta * momS[i]);
  dout[1 + (size_t)CAP * DMEM + i] = sn;       // S_new (in-place over grad)
  dout[1 + i] = fmaf(oma, mem[i], sn);         // M_new
}

extern "C" void kernel_launch(void* const* d_in, const int* in_sizes, int n_in,
                              void* d_out, int out_size, void* d_ws, size_t ws_size,
                              hipStream_t stream) {
  const float* x    = (const float*)d_in[0];
  const float* mem  = (const float*)d_in[1];
  const float* momS = (const float*)d_in[2];
  const float* Wk   = (const float*)d_in[3];
  const float* bk   = (const float*)d_in[4];
  const float* Wv   = (const float*)d_in[5];
  const float* bv   = (const float*)d_in[6];
  const float* fw1  = (const float*)d_in[7];
  const float* fb1  = (const float*)d_in[8];
  const float* fw2  = (const float*)d_in[9];
  const float* fb2  = (const float*)d_in[10];
  const float* dw1  = (const float*)d_in[11];
  const float* db1  = (const float*)d_in[12];
  const float* dw2  = (const float*)d_in[13];
  const float* db2  = (const float*)d_in[14];

  float* out = (float*)d_out;
  float* wsf = (float*)d_ws;

  // small scratch in ws (~1.2 MB)
  float* scal   = wsf;                    // 16
  float* pooled = wsf + 16;               // 2048
  float* kbuf   = wsf + 2064;             // 131072
  float* vbuf   = kbuf + 131072;          // 131072
  float* gdr8   = vbuf + 131072;          // 2048
  float* mfb    = gdr8 + 2048;            // 2048
  float* linvb  = mfb + 2048;             // 2048
  float* msb    = linvb + 2048;           // 16384
  float* lsb    = msb + 16384;            // 16384
  float* lossp  = lsb + 16384;            // 512
  float* gnsqp  = lossp + 512;            // 1024

  // big scratch parked inside d_out's M_new slot (dead until k_upd), 16B-aligned
  float* rsb = out + 4;                                    // 1,048,576 f32
  unsigned short* Msb = (unsigned short*)(out + 4 + 1048576);        // 8 MB
  unsigned short* kb  = (unsigned short*)(out + 4 + 1048576 + 2097152);
  unsigned short* kbT = kb + 131072;
  unsigned short* gb  = kbT + 131072;
  unsigned short* gbT = gb + 131072;
  float* grad = out + 1 + (size_t)CAP * DMEM;              // S_new slot

  k_packm<<<2048, 256, 0, stream>>>(mem, Msb);
  k_proj <<<NTOT, 64, 0, stream>>>(x, Wk, bk, Wv, bv, kbuf, vbuf, kb, kbT);
  k_pool <<<8, 256, 0, stream>>>(x, pooled);
  k_gates<<<1, 128, 0, stream>>>(pooled, fw1, fb1, fw2, fb2, dw1, db1, dw2, db2, scal);
  k_fwd  <<<(NTOT / FW_NT) * NSPLIT, 256, 0, stream>>>(kbuf, mem, msb, lsb, rsb);
  k_comb <<<NTOT / 4, 256, 0, stream>>>(msb, lsb, rsb, vbuf, gb, gbT, gdr8, mfb, linvb, lossp);
  k_bwd2 <<<CAP / 64, 256, 0, stream>>>(kb, kbT, gb, gbT, Msb, mfb, linvb, gdr8, grad, gnsqp);
  k_fin  <<<1, 256, 0, stream>>>(gnsqp, lossp, scal);
  k_upd  <<<(CAP * DMEM) / 256, 256, 0, stream>>>(mem, momS, grad, scal, out);
}

// Round 3
// 851.063 us; speedup vs baseline: 3.4441x; 1.9261x over previous
//
#include <hip/hip_runtime.h>
#include <math.h>

#define D_MODEL 1024
#define DMEM 64
#define CAP 65536
#define SEQ 1024
#define NTOT 2048      // B*S
#define GATE_H 32
#define THETA 0.01f
#define ISQD 0.125f    // 1/sqrt(64)
#define NSPLIT 8
#define CSPL (CAP / NSPLIT)   // 8192
#define GN_BLOCKS (CAP / 64)  // 1024

typedef float f32x4 __attribute__((ext_vector_type(4)));
typedef short bf16x8 __attribute__((ext_vector_type(8)));
typedef unsigned int u32x4 __attribute__((ext_vector_type(4)));

#define MFMA16(a, b, c) __builtin_amdgcn_mfma_f32_16x16x32_bf16(a, b, c, 0, 0, 0)

__device__ inline unsigned short f2bf(float f) {
  union { float f; unsigned u; } v; v.f = f;
  unsigned r = v.u + 0x7FFFu + ((v.u >> 16) & 1u);
  return (unsigned short)(r >> 16);
}
__device__ inline unsigned pk2(float a, float b) {
  return (unsigned)f2bf(a) | ((unsigned)f2bf(b) << 16);
}

// ---------------- K0: Msb = bf16(mem*0.125); MsbT = bf16(mem)^T ----------------
__global__ __launch_bounds__(256) void k_packm(const float* __restrict__ mem,
                                               unsigned short* __restrict__ Msb,
                                               unsigned short* __restrict__ MsbT) {
  size_t gid = (size_t)blockIdx.x * 256 + threadIdx.x;  // CAP*64/8 threads
  int c = (int)(gid >> 3);
  int dc = ((int)gid & 7) * 8;
  const float* src = mem + (size_t)c * DMEM + dc;
  float4 a = *(const float4*)(src);
  float4 b = *(const float4*)(src + 4);
  union { unsigned short s[8]; u32x4 v; } o;   // scaled
  o.s[0] = f2bf(a.x * ISQD); o.s[1] = f2bf(a.y * ISQD);
  o.s[2] = f2bf(a.z * ISQD); o.s[3] = f2bf(a.w * ISQD);
  o.s[4] = f2bf(b.x * ISQD); o.s[5] = f2bf(b.y * ISQD);
  o.s[6] = f2bf(b.z * ISQD); o.s[7] = f2bf(b.w * ISQD);
  *(u32x4*)(Msb + (size_t)c * DMEM + dc) = o.v;
  unsigned short t[8];                          // unscaled, transposed
  t[0] = f2bf(a.x); t[1] = f2bf(a.y); t[2] = f2bf(a.z); t[3] = f2bf(a.w);
  t[4] = f2bf(b.x); t[5] = f2bf(b.y); t[6] = f2bf(b.z); t[7] = f2bf(b.w);
#pragma unroll
  for (int j = 0; j < 8; ++j) MsbT[(size_t)(dc + j) * CAP + c] = t[j];
}

// ---------------- K1: k = x@Wk+bk (bf16 + bf16^T), v = x@Wv+bv (f32) ----------------
__global__ __launch_bounds__(64) void k_proj(const float* __restrict__ x,
    const float* __restrict__ Wk, const float* __restrict__ bk,
    const float* __restrict__ Wv, const float* __restrict__ bv,
    float* __restrict__ vout,
    unsigned short* __restrict__ kb, unsigned short* __restrict__ kbT) {
  __shared__ __align__(16) float xs[D_MODEL];
  int n = blockIdx.x;
  int j = threadIdx.x;
  const float4* xrow = (const float4*)(x + (size_t)n * D_MODEL);
  float4* xs4 = (float4*)xs;
#pragma unroll
  for (int q = 0; q < 4; ++q) xs4[j + 64 * q] = xrow[j + 64 * q];
  __syncthreads();
  float ak = bk[j], av = bv[j];
#pragma unroll 8
  for (int i = 0; i < D_MODEL; ++i) {
    float xv = xs[i];
    ak = fmaf(xv, Wk[i * DMEM + j], ak);
    av = fmaf(xv, Wv[i * DMEM + j], av);
  }
  vout[n * DMEM + j] = av;
  kb[n * DMEM + j] = f2bf(ak);
  kbT[j * NTOT + n] = f2bf(ak);
}

// ---------------- K2: x_pooled = mean_s x ----------------
__global__ __launch_bounds__(256) void k_pool(const float* __restrict__ x,
                                              float* __restrict__ pooled) {
  int idx = blockIdx.x * 256 + threadIdx.x;
  int b = idx >> 10, j = idx & 1023;
  const float* base = x + (size_t)b * SEQ * D_MODEL + j;
  float s = 0.f;
  for (int t = 0; t < SEQ; ++t) s += base[(size_t)t * D_MODEL];
  pooled[idx] = s * (1.0f / SEQ);
}

// ---------------- K3: gates -> alpha, eta ----------------
__global__ __launch_bounds__(128) void k_gates(const float* __restrict__ pooled,
    const float* __restrict__ fw1, const float* __restrict__ fb1,
    const float* __restrict__ fw2, const float* __restrict__ fb2,
    const float* __restrict__ dw1, const float* __restrict__ db1,
    const float* __restrict__ dw2, const float* __restrict__ db2,
    float* __restrict__ scal) {
  __shared__ float hsh[2][2][GATE_H];
  __shared__ float outs[2][2];
  int t = threadIdx.x;
  int gate = t >> 6, b = (t >> 5) & 1, h = t & 31;
  const float* w1 = gate ? dw1 : fw1;
  const float* b1 = gate ? db1 : fb1;
  float z = b1[h];
  const float* prow = pooled + b * D_MODEL;
  for (int i = 0; i < D_MODEL; ++i) z = fmaf(prow[i], w1[i * GATE_H + h], z);
  float sig = 1.f / (1.f + __expf(-z));
  hsh[gate][b][h] = z * sig;
  __syncthreads();
  if (t < 4) {
    int gg = t >> 1, bb = t & 1;
    const float* w2 = gg ? dw2 : fw2;
    float zz = gg ? db2[0] : fb2[0];
    for (int hh = 0; hh < GATE_H; ++hh) zz += hsh[gg][bb][hh] * w2[hh];
    outs[gg][bb] = 1.f / (1.f + __expf(-zz));
  }
  __syncthreads();
  if (t == 0) {
    scal[0] = 0.5f * (outs[0][0] + outs[0][1]);  // alpha
    scal[1] = 0.5f * (outs[1][0] + outs[1][1]);  // eta
  }
}

// ---------------- K4: MFMA flash forward (no-max softmax) ----------------
// grid = 128 n-groups * 8 splits; sp = blockIdx&7 (XCD-pinned split).
// 4 waves; each wave: same 16 n-rows, disjoint 32-c tiles (stride 128).
// S^T = mfma(Msb_rows_c, k_cols_n) -> lane(u,p): n=p, c=4u+r (+16).
// PV: retrieved^T = mfma(MsbT_rows_d, w^T via LDS) -> racc[d][n].
__global__ __launch_bounds__(256, 4) void k_fwd2(
    const unsigned short* __restrict__ kb,
    const unsigned short* __restrict__ Msb,
    const unsigned short* __restrict__ MsbT,
    float* __restrict__ l_s, float* __restrict__ r_s) {
  __shared__ unsigned wt[4][16 * 20];     // per-wave w^T tile [n=16][c=32] bf16, pitch 40
  __shared__ float rt[4][64][18];         // per-wave retrieved^T partials
  int tid = threadIdx.x;
  int wv = tid >> 6, lane = tid & 63;
  int u = lane >> 4, p = lane & 15;
  int sp = blockIdx.x & 7, ng = blockIdx.x >> 3;
  int n0 = ng * 16;

  const unsigned short* kbase = kb + (size_t)(n0 + p) * DMEM + u * 8;
  bf16x8 bk0 = *(const bf16x8*)(kbase);
  bf16x8 bk1 = *(const bf16x8*)(kbase + 32);

  f32x4 racc[4];
#pragma unroll
  for (int q = 0; q < 4; ++q) racc[q] = (f32x4){0.f, 0.f, 0.f, 0.f};
  float esum = 0.f;

  int c0base = sp * CSPL + wv * 32;
  for (int it = 0; it < CSPL / 128; ++it) {
    int c0 = c0base + it * 128;
    const unsigned short* mb0 = Msb + (size_t)(c0 + p) * DMEM + u * 8;
    const unsigned short* mb1 = Msb + (size_t)(c0 + 16 + p) * DMEM + u * 8;
    bf16x8 aM00 = *(const bf16x8*)(mb0);
    bf16x8 aM01 = *(const bf16x8*)(mb0 + 32);
    bf16x8 aM10 = *(const bf16x8*)(mb1);
    bf16x8 aM11 = *(const bf16x8*)(mb1 + 32);
    f32x4 s0 = (f32x4){0.f, 0.f, 0.f, 0.f}, s1 = s0;
    s0 = MFMA16(aM00, bk0, s0);  s0 = MFMA16(aM01, bk1, s0);
    s1 = MFMA16(aM10, bk0, s1);  s1 = MFMA16(aM11, bk1, s1);

    float w00 = __expf(s0.x), w01 = __expf(s0.y), w02 = __expf(s0.z), w03 = __expf(s0.w);
    float w10 = __expf(s1.x), w11 = __expf(s1.y), w12 = __expf(s1.z), w13 = __expf(s1.w);
    esum += ((w00 + w01) + (w02 + w03)) + ((w10 + w11) + (w12 + w13));

    unsigned* wr = &wt[wv][p * 20];
    wr[2 * u + 0] = pk2(w00, w01);
    wr[2 * u + 1] = pk2(w02, w03);
    wr[8 + 2 * u + 0] = pk2(w10, w11);
    wr[8 + 2 * u + 1] = pk2(w12, w13);
    asm volatile("" ::: "memory");
    u32x4 b4 = *(const u32x4*)&wt[wv][p * 20 + u * 4];
    asm volatile("" ::: "memory");
    bf16x8 bw = __builtin_bit_cast(bf16x8, b4);
#pragma unroll
    for (int df = 0; df < 4; ++df) {
      bf16x8 aT = *(const bf16x8*)(MsbT + (size_t)(df * 16 + p) * CAP + c0 + u * 8);
      racc[df] = MFMA16(aT, bw, racc[df]);
    }
  }

  // l partial per sub-split (wave)
  esum += __shfl_xor(esum, 16, 64);
  esum += __shfl_xor(esum, 32, 64);
  if (u == 0) l_s[(sp * 4 + wv) * NTOT + n0 + p] = esum;

  // block-combine retrieved^T across waves -> coalesced r_s store
#pragma unroll
  for (int df = 0; df < 4; ++df)
#pragma unroll
    for (int r = 0; r < 4; ++r) rt[wv][df * 16 + 4 * u + r][p] = racc[df][r];
  __syncthreads();
  int n = tid >> 4;
  int d4 = (tid & 15) * 4;
  float4 o;
  o.x = ((rt[0][d4 + 0][n] + rt[1][d4 + 0][n]) + (rt[2][d4 + 0][n] + rt[3][d4 + 0][n]));
  o.y = ((rt[0][d4 + 1][n] + rt[1][d4 + 1][n]) + (rt[2][d4 + 1][n] + rt[3][d4 + 1][n]));
  o.z = ((rt[0][d4 + 2][n] + rt[1][d4 + 2][n]) + (rt[2][d4 + 2][n] + rt[3][d4 + 2][n]));
  o.w = ((rt[0][d4 + 3][n] + rt[1][d4 + 3][n]) + (rt[2][d4 + 3][n] + rt[3][d4 + 3][n]));
  *(float4*)&r_s[((size_t)sp * NTOT + n0 + n) * DMEM + d4] = o;
}

// ---------------- K5: combine splits, loss, g (bf16), gdotr ----------------
__global__ __launch_bounds__(256) void k_comb(
    const float* __restrict__ l_s, const float* __restrict__ r_s,
    const float* __restrict__ v,
    unsigned short* __restrict__ gb, unsigned short* __restrict__ gbT,
    float* __restrict__ gdr8, float* __restrict__ linv,
    float* __restrict__ lossp) {
  __shared__ float lsum[4];
  int tid = threadIdx.x;
  int nl = tid >> 6, dd = tid & 63;
  int n = blockIdx.x * 4 + nl;
  float l = 0.f;
#pragma unroll
  for (int s = 0; s < 32; ++s) l += l_s[s * NTOT + n];
  float r = 0.f;
#pragma unroll
  for (int s = 0; s < NSPLIT; ++s)
    r += r_s[((size_t)s * NTOT + n) * DMEM + dd];
  float li = 1.f / l;
  float ret = r * li;
  float vv = v[n * DMEM + dd];
  const float c0 = 2.f / (float)(NTOT * DMEM);
  float diff = ret - vv;
  float gv = c0 * diff;
  gb[n * DMEM + dd] = f2bf(gv);
  gbT[dd * NTOT + n] = f2bf(gv);
  float gr = gv * ret;
  float lp = diff * diff;
#pragma unroll
  for (int off = 1; off < 64; off <<= 1) {
    gr += __shfl_xor(gr, off, 64);
    lp += __shfl_xor(lp, off, 64);
  }
  if (dd == 0) {
    gdr8[n] = gr * ISQD;
    linv[n] = li;
    lsum[nl] = lp;
  }
  __syncthreads();
  if (tid == 0)
    lossp[blockIdx.x] =
        (lsum[0] + lsum[1] + lsum[2] + lsum[3]) * (1.f / (float)(NTOT * DMEM));
}

// ---------------- K6: MFMA backward ----------------
__global__ __launch_bounds__(256, 3) void k_bwd2(
    const unsigned short* __restrict__ kb, const unsigned short* __restrict__ kbT,
    const unsigned short* __restrict__ gb, const unsigned short* __restrict__ gbT,
    const unsigned short* __restrict__ Msb,
    const float* __restrict__ linv, const float* __restrict__ gdr8,
    float* __restrict__ grad, float* __restrict__ gnsqp) {
  __shared__ unsigned wt[4][16 * 20];
  __shared__ unsigned ct[4][16 * 20];
  __shared__ float red[4];
  int tid = threadIdx.x;
  int wv = tid >> 6, lane = tid & 63;
  int u = lane >> 4, p = lane & 15;
  int cw = blockIdx.x * 64 + wv * 16;

  bf16x8 bM0 = *(const bf16x8*)(Msb + (size_t)(cw + p) * DMEM + u * 8);
  bf16x8 bM1 = *(const bf16x8*)(Msb + (size_t)(cw + p) * DMEM + 32 + u * 8);

  f32x4 gacc[4];
#pragma unroll
  for (int q = 0; q < 4; ++q) gacc[q] = (f32x4){0.f, 0.f, 0.f, 0.f};

  for (int nt = 0; nt < NTOT / 32; ++nt) {
    int n0 = nt * 32;
    const unsigned short* kbase = kb + (size_t)(n0 + p) * DMEM + u * 8;
    const unsigned short* gbase = gb + (size_t)(n0 + p) * DMEM + u * 8;
    bf16x8 ak00 = *(const bf16x8*)(kbase);
    bf16x8 ak01 = *(const bf16x8*)(kbase + 32);
    bf16x8 ak10 = *(const bf16x8*)(kbase + 16 * DMEM);
    bf16x8 ak11 = *(const bf16x8*)(kbase + 16 * DMEM + 32);
    bf16x8 ag00 = *(const bf16x8*)(gbase);
    bf16x8 ag01 = *(const bf16x8*)(gbase + 32);
    bf16x8 ag10 = *(const bf16x8*)(gbase + 16 * DMEM);
    bf16x8 ag11 = *(const bf16x8*)(gbase + 16 * DMEM + 32);

    f32x4 s0 = (f32x4){0.f, 0.f, 0.f, 0.f}, s1 = s0, pg0 = s0, pg1 = s0;
    s0 = MFMA16(ak00, bM0, s0);  s0 = MFMA16(ak01, bM1, s0);
    s1 = MFMA16(ak10, bM0, s1);  s1 = MFMA16(ak11, bM1, s1);
    pg0 = MFMA16(ag00, bM0, pg0); pg0 = MFMA16(ag01, bM1, pg0);
    pg1 = MFMA16(ag10, bM0, pg1); pg1 = MFMA16(ag11, bM1, pg1);

    float4 l0 = *(const float4*)(linv + n0 + u * 4);
    float4 l1 = *(const float4*)(linv + n0 + 16 + u * 4);
    float4 d0 = *(const float4*)(gdr8 + n0 + u * 4);
    float4 d1 = *(const float4*)(gdr8 + n0 + 16 + u * 4);

    float w00 = __expf(s0.x) * l0.x;
    float w01 = __expf(s0.y) * l0.y;
    float w02 = __expf(s0.z) * l0.z;
    float w03 = __expf(s0.w) * l0.w;
    float w10 = __expf(s1.x) * l1.x;
    float w11 = __expf(s1.y) * l1.y;
    float w12 = __expf(s1.z) * l1.z;
    float w13 = __expf(s1.w) * l1.w;
    float c00 = w00 * (pg0.x - d0.x);
    float c01 = w01 * (pg0.y - d0.y);
    float c02 = w02 * (pg0.z - d0.z);
    float c03 = w03 * (pg0.w - d0.w);
    float c10 = w10 * (pg1.x - d1.x);
    float c11 = w11 * (pg1.y - d1.y);
    float c12 = w12 * (pg1.z - d1.z);
    float c13 = w13 * (pg1.w - d1.w);

    asm volatile("" ::: "memory");
    unsigned* wr = &wt[wv][p * 20];
    unsigned* cr = &ct[wv][p * 20];
    wr[2 * u + 0] = pk2(w00, w01);
    wr[2 * u + 1] = pk2(w02, w03);
    wr[8 + 2 * u + 0] = pk2(w10, w11);
    wr[8 + 2 * u + 1] = pk2(w12, w13);
    cr[2 * u + 0] = pk2(c00, c01);
    cr[2 * u + 1] = pk2(c02, c03);
    cr[8 + 2 * u + 0] = pk2(c10, c11);
    cr[8 + 2 * u + 1] = pk2(c12, c13);
    asm volatile("" ::: "memory");
    u32x4 aw4 = *(const u32x4*)&wt[wv][p * 20 + u * 4];
    u32x4 ac4 = *(const u32x4*)&ct[wv][p * 20 + u * 4];
    asm volatile("" ::: "memory");
    bf16x8 aw = __builtin_bit_cast(bf16x8, aw4);
    bf16x8 ac = __builtin_bit_cast(bf16x8, ac4);
#pragma unroll
    for (int df = 0; df < 4; ++df) {
      bf16x8 bg = *(const bf16x8*)(gbT + (size_t)(df * 16 + p) * NTOT + n0 + u * 8);
      bf16x8 bk2 = *(const bf16x8*)(kbT + (size_t)(df * 16 + p) * NTOT + n0 + u * 8);
      gacc[df] = MFMA16(aw, bg, gacc[df]);
      gacc[df] = MFMA16(ac, bk2, gacc[df]);
    }
  }

  float ss = 0.f;
#pragma unroll
  for (int df = 0; df < 4; ++df) {
#pragma unroll
    for (int r = 0; r < 4; ++r) {
      float gv = gacc[df][r];
      grad[(size_t)(cw + 4 * u + r) * DMEM + df * 16 + p] = gv;
      ss = fmaf(gv, gv, ss);
    }
  }
#pragma unroll
  for (int off = 1; off < 64; off <<= 1) ss += __shfl_xor(ss, off, 64);
  if (lane == 0) red[wv] = ss;
  __syncthreads();
  if (tid == 0) gnsqp[blockIdx.x] = red[0] + red[1] + red[2] + red[3];
}

// ---------------- K7: final scalar reduce ----------------
__global__ __launch_bounds__(256) void k_fin(const float* __restrict__ gnsqp,
                                             const float* __restrict__ lossp,
                                             float* __restrict__ scal) {
  __shared__ float sh[8];
  int tid = threadIdx.x;
  float s1 = 0.f, s2 = 0.f;
  for (int i = tid; i < GN_BLOCKS; i += 256) s1 += gnsqp[i];
  for (int i = tid; i < NTOT / 4; i += 256) s2 += lossp[i];
#pragma unroll
  for (int off = 1; off < 64; off <<= 1) {
    s1 += __shfl_xor(s1, off, 64);
    s2 += __shfl_xor(s2, off, 64);
  }
  if ((tid & 63) == 0) { sh[(tid >> 6) * 2] = s1; sh[(tid >> 6) * 2 + 1] = s2; }
  __syncthreads();
  if (tid == 0) {
    float gnsq = sh[0] + sh[2] + sh[4] + sh[6];
    float loss = sh[1] + sh[3] + sh[5] + sh[7];
    float gn = sqrtf(gnsq);
    float clip = (gn > 1.0f) ? (1.0f / gn) : 1.0f;
    scal[2] = THETA * clip;
    scal[3] = loss;
  }
}

// ---------------- K8: M_new / S_new / loss write ----------------
__global__ __launch_bounds__(256) void k_upd(const float* __restrict__ mem,
    const float* __restrict__ momS, const float* __restrict__ grad,
    const float* __restrict__ scal, float* __restrict__ dout) {
  size_t i = (size_t)blockIdx.x * 256 + threadIdx.x;
  float oma = 1.f - scal[0];
  float eta = scal[1];
  float th = scal[2];
  if (i == 0) dout[0] = scal[3];
  float gr = grad[i];
  float sn = fmaf(-th, gr, eta * momS[i]);
  dout[1 + (size_t)CAP * DMEM + i] = sn;       // S_new (in-place over grad)
  dout[1 + i] = fmaf(oma, mem[i], sn);         // M_new
}

extern "C" void kernel_launch(void* const* d_in, const int* in_sizes, int n_in,
                              void* d_out, int out_size, void* d_ws, size_t ws_size,
                              hipStream_t stream) {
  const float* x    = (const float*)d_in[0];
  const float* mem  = (const float*)d_in[1];
  const float* momS = (const float*)d_in[2];
  const float* Wk   = (const float*)d_in[3];
  const float* bk   = (const float*)d_in[4];
  const float* Wv   = (const float*)d_in[5];
  const float* bv   = (const float*)d_in[6];
  const float* fw1  = (const float*)d_in[7];
  const float* fb1  = (const float*)d_in[8];
  const float* fw2  = (const float*)d_in[9];
  const float* fb2  = (const float*)d_in[10];
  const float* dw1  = (const float*)d_in[11];
  const float* db1  = (const float*)d_in[12];
  const float* dw2  = (const float*)d_in[13];
  const float* db2  = (const float*)d_in[14];

  float* out = (float*)d_out;
  float* wsf = (float*)d_ws;

  // ws scratch (~1.9 MB)
  float* scal   = wsf;                    // 16
  float* pooled = wsf + 16;               // 2048
  float* vbuf   = wsf + 2064;             // 131072
  float* gdr8   = vbuf + 131072;          // 2048
  float* linvb  = gdr8 + 2048;            // 2048
  float* lsb    = linvb + 2048;           // 32*2048 = 65536
  float* lossp  = lsb + 65536;            // 512
  float* gnsqp  = lossp + 512;            // 1024
  unsigned short* kb  = (unsigned short*)(gnsqp + 1024);  // 131072 shorts each
  unsigned short* kbT = kb + 131072;
  unsigned short* gb  = kbT + 131072;
  unsigned short* gbT = gb + 131072;

  // M_new slot: Msb (scaled) + MsbT (unscaled transpose), both bf16 (16 MB)
  unsigned short* Msb  = (unsigned short*)(out + 4);
  unsigned short* MsbT = Msb + (size_t)CAP * DMEM;   // ends 3 floats into S_new slot (dead then)
  // S_new slot: r_s (1 MB, dead before grad) then grad (written by k_bwd2)
  float* rsb  = out + 4 + (size_t)CAP * DMEM + 4;    // 8*2048*64 = 1,048,576 f32
  float* grad = out + 1 + (size_t)CAP * DMEM;

  k_packm<<<(CAP * DMEM / 8) / 256, 256, 0, stream>>>(mem, Msb, MsbT);
  k_proj <<<NTOT, 64, 0, stream>>>(x, Wk, bk, Wv, bv, vbuf, kb, kbT);
  k_pool <<<8, 256, 0, stream>>>(x, pooled);
  k_gates<<<1, 128, 0, stream>>>(pooled, fw1, fb1, fw2, fb2, dw1, db1, dw2, db2, scal);
  k_fwd2 <<<(NTOT / 16) * NSPLIT, 256, 0, stream>>>(kb, Msb, MsbT, lsb, rsb);
  k_comb <<<NTOT / 4, 256, 0, stream>>>(lsb, rsb, vbuf, gb, gbT, gdr8, linvb, lossp);
  k_bwd2 <<<CAP / 64, 256, 0, stream>>>(kb, kbT, gb, gbT, Msb, linvb, gdr8, grad, gnsqp);
  k_fin  <<<1, 256, 0, stream>>>(gnsqp, lossp, scal);
  k_upd  <<<(CAP * DMEM) / 256, 256, 0, stream>>>(mem, momS, grad, scal, out);
}

// Round 4
// 390.100 us; speedup vs baseline: 7.5138x; 2.1817x over previous
//
#include <hip/hip_runtime.h>
#include <math.h>

#define D_MODEL 1024
#define DMEM 64
#define CAP 65536
#define SEQ 1024
#define NTOT 2048      // B*S
#define GATE_H 32
#define THETA 0.01f
#define ISQD 0.125f    // 1/sqrt(64)
#define NSPLIT 8
#define CSPL (CAP / NSPLIT)   // 8192
#define GN_BLOCKS (CAP / 64)  // 1024

typedef float f32x4 __attribute__((ext_vector_type(4)));
typedef short bf16x8 __attribute__((ext_vector_type(8)));
typedef unsigned int u32x4 __attribute__((ext_vector_type(4)));

#define MFMA16(a, b, c) __builtin_amdgcn_mfma_f32_16x16x32_bf16(a, b, c, 0, 0, 0)

__device__ inline unsigned short f2bf(float f) {
  union { float f; unsigned u; } v; v.f = f;
  unsigned r = v.u + 0x7FFFu + ((v.u >> 16) & 1u);
  return (unsigned short)(r >> 16);
}
__device__ inline unsigned pk2(float a, float b) {
  return (unsigned)f2bf(a) | ((unsigned)f2bf(b) << 16);
}

// ---------------- K0: Msb = bf16(mem*0.125); MsbT = same, transposed ----------------
__global__ __launch_bounds__(256) void k_packm(const float* __restrict__ mem,
                                               unsigned short* __restrict__ Msb,
                                               unsigned short* __restrict__ MsbT) {
  size_t gid = (size_t)blockIdx.x * 256 + threadIdx.x;
  int c = (int)(gid >> 3);
  int dc = ((int)gid & 7) * 8;
  const float* src = mem + (size_t)c * DMEM + dc;
  float4 a = *(const float4*)(src);
  float4 b = *(const float4*)(src + 4);
  union { unsigned short s[8]; u32x4 v; } o;   // scaled by 1/sqrt(d)
  o.s[0] = f2bf(a.x * ISQD); o.s[1] = f2bf(a.y * ISQD);
  o.s[2] = f2bf(a.z * ISQD); o.s[3] = f2bf(a.w * ISQD);
  o.s[4] = f2bf(b.x * ISQD); o.s[5] = f2bf(b.y * ISQD);
  o.s[6] = f2bf(b.z * ISQD); o.s[7] = f2bf(b.w * ISQD);
  *(u32x4*)(Msb + (size_t)c * DMEM + dc) = o.v;
#pragma unroll
  for (int j = 0; j < 8; ++j) MsbT[(size_t)(dc + j) * CAP + c] = o.s[j];
}

// ---------------- K1: k = x@Wk+bk (bf16 + bf16^T), v = x@Wv+bv (f32) ----------------
__global__ __launch_bounds__(64) void k_proj(const float* __restrict__ x,
    const float* __restrict__ Wk, const float* __restrict__ bk,
    const float* __restrict__ Wv, const float* __restrict__ bv,
    float* __restrict__ vout,
    unsigned short* __restrict__ kb, unsigned short* __restrict__ kbT) {
  __shared__ __align__(16) float xs[D_MODEL];
  int n = blockIdx.x;
  int j = threadIdx.x;
  const float4* xrow = (const float4*)(x + (size_t)n * D_MODEL);
  float4* xs4 = (float4*)xs;
#pragma unroll
  for (int q = 0; q < 4; ++q) xs4[j + 64 * q] = xrow[j + 64 * q];
  __syncthreads();
  float ak = bk[j], av = bv[j];
#pragma unroll 8
  for (int i = 0; i < D_MODEL; ++i) {
    float xv = xs[i];
    ak = fmaf(xv, Wk[i * DMEM + j], ak);
    av = fmaf(xv, Wv[i * DMEM + j], av);
  }
  vout[n * DMEM + j] = av;
  kb[n * DMEM + j] = f2bf(ak);
  kbT[j * NTOT + n] = f2bf(ak);
}

// ---------------- K2: x_pooled = mean_s x ----------------
__global__ __launch_bounds__(256) void k_pool(const float* __restrict__ x,
                                              float* __restrict__ pooled) {
  int idx = blockIdx.x * 256 + threadIdx.x;
  int b = idx >> 10, j = idx & 1023;
  const float* base = x + (size_t)b * SEQ * D_MODEL + j;
  float s = 0.f;
  for (int t = 0; t < SEQ; ++t) s += base[(size_t)t * D_MODEL];
  pooled[idx] = s * (1.0f / SEQ);
}

// ---------------- K3: gates -> alpha, eta ----------------
__global__ __launch_bounds__(128) void k_gates(const float* __restrict__ pooled,
    const float* __restrict__ fw1, const float* __restrict__ fb1,
    const float* __restrict__ fw2, const float* __restrict__ fb2,
    const float* __restrict__ dw1, const float* __restrict__ db1,
    const float* __restrict__ dw2, const float* __restrict__ db2,
    float* __restrict__ scal) {
  __shared__ float hsh[2][2][GATE_H];
  __shared__ float outs[2][2];
  int t = threadIdx.x;
  int gate = t >> 6, b = (t >> 5) & 1, h = t & 31;
  const float* w1 = gate ? dw1 : fw1;
  const float* b1 = gate ? db1 : fb1;
  float z = b1[h];
  const float* prow = pooled + b * D_MODEL;
  for (int i = 0; i < D_MODEL; ++i) z = fmaf(prow[i], w1[i * GATE_H + h], z);
  float sig = 1.f / (1.f + __expf(-z));
  hsh[gate][b][h] = z * sig;
  __syncthreads();
  if (t < 4) {
    int gg = t >> 1, bb = t & 1;
    const float* w2 = gg ? dw2 : fw2;
    float zz = gg ? db2[0] : fb2[0];
    for (int hh = 0; hh < GATE_H; ++hh) zz += hsh[gg][bb][hh] * w2[hh];
    outs[gg][bb] = 1.f / (1.f + __expf(-zz));
  }
  __syncthreads();
  if (t == 0) {
    scal[0] = 0.5f * (outs[0][0] + outs[0][1]);  // alpha
    scal[1] = 0.5f * (outs[1][0] + outs[1][1]);  // eta
  }
}

// ---------------- K4: MFMA forward v3 (LDS-staged, no divergent inner loads) ----------------
// grid = 128 n-groups * 8 splits; sp = blockIdx&7 (XCD-pinned split).
// Block stages M tile [128c][64d] (pitch 72) + M^T tile [64d][128c] (pitch 136).
// 4 waves share tiles; wave wv owns c-slice [wv*32, wv*32+32) of each tile.
// Scores S^T: A = M rows c (LDS b128), B = k cols n (persistent regs).
// PV: A = M^T rows d (LDS b128), B = w^T via per-wave LDS round trip.
__global__ __launch_bounds__(256, 3) void k_fwd3(
    const unsigned short* __restrict__ kb,
    const unsigned short* __restrict__ Msb,
    const unsigned short* __restrict__ MsbT,
    float* __restrict__ l_s, float* __restrict__ r_s) {
  __shared__ __align__(16) char smem[40960];
  short* Mt  = (short*)smem;                    // [128][72]
  short* MTt = Mt + 128 * 72;                   // [64][136]
  unsigned* wtb = (unsigned*)(MTt + 64 * 136);  // 4 waves x [16][20] u32
  int tid = threadIdx.x;
  int wv = tid >> 6, lane = tid & 63;
  int u = lane >> 4, p = lane & 15;
  int sp = blockIdx.x & 7, ng = blockIdx.x >> 3;
  int n0 = ng * 16;
  unsigned* wtp = wtb + wv * 320;

  // persistent B-frags: k rows for this block's 16 n (one-time divergent load)
  const unsigned short* kbase = kb + (size_t)(n0 + p) * DMEM + u * 8;
  bf16x8 bk0 = *(const bf16x8*)(kbase);
  bf16x8 bk1 = *(const bf16x8*)(kbase + 32);

  // staging decomposition (4 granules per array per thread)
  int mc = tid >> 3, mdh = tid & 7;   // Mtile: c = mc+32q, d = mdh*8
  int td = tid >> 4, tch = tid & 15;  // MTtile: d = td+16q, c = tch*8

  int c0base = sp * CSPL;
  u32x4 sM[4], sT[4];
#pragma unroll
  for (int q = 0; q < 4; ++q) {
    sM[q] = *(const u32x4*)(Msb + (size_t)(c0base + mc + 32 * q) * DMEM + mdh * 8);
    sT[q] = *(const u32x4*)(MsbT + (size_t)(td + 16 * q) * CAP + c0base + tch * 8);
  }

  f32x4 racc[4];
#pragma unroll
  for (int q = 0; q < 4; ++q) racc[q] = (f32x4){0.f, 0.f, 0.f, 0.f};
  float esum = 0.f;

  const int NT = CSPL / 128;  // 64
  for (int it = 0; it < NT; ++it) {
    __syncthreads();
#pragma unroll
    for (int q = 0; q < 4; ++q) {
      *(u32x4*)(Mt + (mc + 32 * q) * 72 + mdh * 8) = sM[q];
      *(u32x4*)(MTt + (td + 16 * q) * 136 + tch * 8) = sT[q];
    }
    __syncthreads();
    // prefetch next tile (T14): issue loads before compute
    int itn = (it + 1 < NT) ? it + 1 : it;
    int c0n = c0base + itn * 128;
#pragma unroll
    for (int q = 0; q < 4; ++q) {
      sM[q] = *(const u32x4*)(Msb + (size_t)(c0n + mc + 32 * q) * DMEM + mdh * 8);
      sT[q] = *(const u32x4*)(MsbT + (size_t)(td + 16 * q) * CAP + c0n + tch * 8);
    }
    // scores: D(row c = f*16+4u+r, col n = p)
    f32x4 s[2];
    s[0] = (f32x4){0.f, 0.f, 0.f, 0.f}; s[1] = s[0];
#pragma unroll
    for (int f = 0; f < 2; ++f) {
      bf16x8 a0 = *(const bf16x8*)(Mt + (wv * 32 + f * 16 + p) * 72 + u * 8);
      bf16x8 a1 = *(const bf16x8*)(Mt + (wv * 32 + f * 16 + p) * 72 + 32 + u * 8);
      s[f] = MFMA16(a0, bk0, s[f]);
      s[f] = MFMA16(a1, bk1, s[f]);
    }
    float w00 = __expf(s[0].x), w01 = __expf(s[0].y), w02 = __expf(s[0].z), w03 = __expf(s[0].w);
    float w10 = __expf(s[1].x), w11 = __expf(s[1].y), w12 = __expf(s[1].z), w13 = __expf(s[1].w);
    esum += ((w00 + w01) + (w02 + w03)) + ((w10 + w11) + (w12 + w13));
    asm volatile("" ::: "memory");
    wtp[p * 20 + 2 * u] = pk2(w00, w01);
    wtp[p * 20 + 2 * u + 1] = pk2(w02, w03);
    wtp[p * 20 + 8 + 2 * u] = pk2(w10, w11);
    wtp[p * 20 + 8 + 2 * u + 1] = pk2(w12, w13);
    asm volatile("" ::: "memory");
    u32x4 bw4 = *(const u32x4*)(wtp + p * 20 + u * 4);
    asm volatile("" ::: "memory");
    bf16x8 bw = __builtin_bit_cast(bf16x8, bw4);
#pragma unroll
    for (int df = 0; df < 4; ++df) {
      bf16x8 aT = *(const bf16x8*)(MTt + (df * 16 + p) * 136 + wv * 32 + u * 8);
      racc[df] = MFMA16(aT, bw, racc[df]);
    }
  }

  // l partial per (split, wave)
  esum += __shfl_xor(esum, 16, 64);
  esum += __shfl_xor(esum, 32, 64);
  if (u == 0) l_s[(sp * 4 + wv) * NTOT + n0 + p] = esum;

  // cross-wave combine of retrieved^T via rt (aliased over Mt)
  __syncthreads();
  float* rt = (float*)smem;  // [4][64][17]
#pragma unroll
  for (int df = 0; df < 4; ++df)
#pragma unroll
    for (int r = 0; r < 4; ++r)
      rt[(wv * 64 + df * 16 + 4 * u + r) * 17 + p] = racc[df][r];
  __syncthreads();
  int n = tid >> 4;
  int d4 = (tid & 15) * 4;
  float4 o;
  o.x = (rt[(0 * 64 + d4 + 0) * 17 + n] + rt[(1 * 64 + d4 + 0) * 17 + n]) +
        (rt[(2 * 64 + d4 + 0) * 17 + n] + rt[(3 * 64 + d4 + 0) * 17 + n]);
  o.y = (rt[(0 * 64 + d4 + 1) * 17 + n] + rt[(1 * 64 + d4 + 1) * 17 + n]) +
        (rt[(2 * 64 + d4 + 1) * 17 + n] + rt[(3 * 64 + d4 + 1) * 17 + n]);
  o.z = (rt[(0 * 64 + d4 + 2) * 17 + n] + rt[(1 * 64 + d4 + 2) * 17 + n]) +
        (rt[(2 * 64 + d4 + 2) * 17 + n] + rt[(3 * 64 + d4 + 2) * 17 + n]);
  o.w = (rt[(0 * 64 + d4 + 3) * 17 + n] + rt[(1 * 64 + d4 + 3) * 17 + n]) +
        (rt[(2 * 64 + d4 + 3) * 17 + n] + rt[(3 * 64 + d4 + 3) * 17 + n]);
  *(float4*)&r_s[((size_t)sp * NTOT + n0 + n) * DMEM + d4] = o;
}

// ---------------- K5: combine splits, loss, g (bf16), gdotr ----------------
__global__ __launch_bounds__(256) void k_comb(
    const float* __restrict__ l_s, const float* __restrict__ r_s,
    const float* __restrict__ v,
    unsigned short* __restrict__ gb, unsigned short* __restrict__ gbT,
    float* __restrict__ gdr8, float* __restrict__ linv,
    float* __restrict__ lossp) {
  __shared__ float lsum[4];
  int tid = threadIdx.x;
  int nl = tid >> 6, dd = tid & 63;
  int n = blockIdx.x * 4 + nl;
  float l = 0.f;
#pragma unroll
  for (int s = 0; s < 32; ++s) l += l_s[s * NTOT + n];
  float r = 0.f;
#pragma unroll
  for (int s = 0; s < NSPLIT; ++s)
    r += r_s[((size_t)s * NTOT + n) * DMEM + dd];
  float li = 1.f / l;
  float ret = r * li * 8.0f;   // MsbT was scaled by 0.125 -> compensate exactly
  float vv = v[n * DMEM + dd];
  const float c0 = 2.f / (float)(NTOT * DMEM);
  float diff = ret - vv;
  float gv = c0 * diff;
  gb[n * DMEM + dd] = f2bf(gv);
  gbT[dd * NTOT + n] = f2bf(gv);
  float gr = gv * ret;
  float lp = diff * diff;
#pragma unroll
  for (int off = 1; off < 64; off <<= 1) {
    gr += __shfl_xor(gr, off, 64);
    lp += __shfl_xor(lp, off, 64);
  }
  if (dd == 0) {
    gdr8[n] = gr * ISQD;
    linv[n] = li;
    lsum[nl] = lp;
  }
  __syncthreads();
  if (tid == 0)
    lossp[blockIdx.x] =
        (lsum[0] + lsum[1] + lsum[2] + lsum[3]) * (1.f / (float)(NTOT * DMEM));
}

// ---------------- K6: MFMA backward v3 (LDS-staged) ----------------
// grid = CAP/64 blocks, 4 waves; wave owns 16 c. Per n-tile of 32:
// stage kt/gt [32n][72] + ktT/gtT [64d][40] (coalesced / 16-seg once per block).
// Scores: A = k/g rows n (LDS), B = M cols c (persistent regs).
// grad: A = w^T/coef^T (per-wave LDS round trip), B = G/K cols d (LDS b128).
__global__ __launch_bounds__(256, 3) void k_bwd3(
    const unsigned short* __restrict__ kb, const unsigned short* __restrict__ kbT,
    const unsigned short* __restrict__ gb, const unsigned short* __restrict__ gbT,
    const unsigned short* __restrict__ Msb,
    const float* __restrict__ linv, const float* __restrict__ gdr8,
    float* __restrict__ grad, float* __restrict__ gnsqp) {
  __shared__ __align__(16) char smem[29696];
  __shared__ float red[4];
  short* kt  = (short*)smem;        // [32][72]
  short* gt  = kt + 32 * 72;        // [32][72]
  short* ktT = gt + 32 * 72;        // [64][40]
  short* gtT = ktT + 64 * 40;       // [64][40]
  unsigned* wct = (unsigned*)(gtT + 64 * 40);  // 4 waves x 2 x [16][20]
  int tid = threadIdx.x;
  int wv = tid >> 6, lane = tid & 63;
  int u = lane >> 4, p = lane & 15;
  int cw = blockIdx.x * 64 + wv * 16;
  unsigned* wtp = wct + wv * 640;
  unsigned* ctp = wtp + 320;

  bf16x8 bM0 = *(const bf16x8*)(Msb + (size_t)(cw + p) * DMEM + u * 8);
  bf16x8 bM1 = *(const bf16x8*)(Msb + (size_t)(cw + p) * DMEM + 32 + u * 8);

  f32x4 gacc[4];
#pragma unroll
  for (int q = 0; q < 4; ++q) gacc[q] = (f32x4){0.f, 0.f, 0.f, 0.f};

  int sn = tid >> 3, sdh = tid & 7;   // kt/gt granule: row n, d = sdh*8
  int sd = tid >> 2, sch = tid & 3;   // ktT/gtT granule: row d, n = sch*8

  u32x4 rk, rg, rkT, rgT;
  rk  = *(const u32x4*)(kb + (size_t)sn * DMEM + sdh * 8);
  rg  = *(const u32x4*)(gb + (size_t)sn * DMEM + sdh * 8);
  rkT = *(const u32x4*)(kbT + (size_t)sd * NTOT + sch * 8);
  rgT = *(const u32x4*)(gbT + (size_t)sd * NTOT + sch * 8);

  const int NT = NTOT / 32;  // 64
  for (int it = 0; it < NT; ++it) {
    __syncthreads();
    *(u32x4*)(kt + sn * 72 + sdh * 8) = rk;
    *(u32x4*)(gt + sn * 72 + sdh * 8) = rg;
    *(u32x4*)(ktT + sd * 40 + sch * 8) = rkT;
    *(u32x4*)(gtT + sd * 40 + sch * 8) = rgT;
    __syncthreads();
    int n0 = it * 32;
    int n0n = (it + 1 < NT) ? n0 + 32 : n0;
    rk  = *(const u32x4*)(kb + (size_t)(n0n + sn) * DMEM + sdh * 8);
    rg  = *(const u32x4*)(gb + (size_t)(n0n + sn) * DMEM + sdh * 8);
    rkT = *(const u32x4*)(kbT + (size_t)sd * NTOT + n0n + sch * 8);
    rgT = *(const u32x4*)(gbT + (size_t)sd * NTOT + n0n + sch * 8);

    // scores + pg: D(row n = f*16+4u+r, col c = cw+p)
    f32x4 s0 = (f32x4){0.f, 0.f, 0.f, 0.f}, s1 = s0, pg0 = s0, pg1 = s0;
    {
      bf16x8 a;
      a = *(const bf16x8*)(kt + p * 72 + u * 8);              s0 = MFMA16(a, bM0, s0);
      a = *(const bf16x8*)(kt + p * 72 + 32 + u * 8);         s0 = MFMA16(a, bM1, s0);
      a = *(const bf16x8*)(kt + (16 + p) * 72 + u * 8);       s1 = MFMA16(a, bM0, s1);
      a = *(const bf16x8*)(kt + (16 + p) * 72 + 32 + u * 8);  s1 = MFMA16(a, bM1, s1);
      a = *(const bf16x8*)(gt + p * 72 + u * 8);              pg0 = MFMA16(a, bM0, pg0);
      a = *(const bf16x8*)(gt + p * 72 + 32 + u * 8);         pg0 = MFMA16(a, bM1, pg0);
      a = *(const bf16x8*)(gt + (16 + p) * 72 + u * 8);       pg1 = MFMA16(a, bM0, pg1);
      a = *(const bf16x8*)(gt + (16 + p) * 72 + 32 + u * 8);  pg1 = MFMA16(a, bM1, pg1);
    }
    float4 l0 = *(const float4*)(linv + n0 + u * 4);
    float4 l1 = *(const float4*)(linv + n0 + 16 + u * 4);
    float4 d0 = *(const float4*)(gdr8 + n0 + u * 4);
    float4 d1 = *(const float4*)(gdr8 + n0 + 16 + u * 4);

    float w00 = __expf(s0.x) * l0.x, w01 = __expf(s0.y) * l0.y;
    float w02 = __expf(s0.z) * l0.z, w03 = __expf(s0.w) * l0.w;
    float w10 = __expf(s1.x) * l1.x, w11 = __expf(s1.y) * l1.y;
    float w12 = __expf(s1.z) * l1.z, w13 = __expf(s1.w) * l1.w;
    float c00 = w00 * (pg0.x - d0.x), c01 = w01 * (pg0.y - d0.y);
    float c02 = w02 * (pg0.z - d0.z), c03 = w03 * (pg0.w - d0.w);
    float c10 = w10 * (pg1.x - d1.x), c11 = w11 * (pg1.y - d1.y);
    float c12 = w12 * (pg1.z - d1.z), c13 = w13 * (pg1.w - d1.w);

    asm volatile("" ::: "memory");
    wtp[p * 20 + 2 * u] = pk2(w00, w01);
    wtp[p * 20 + 2 * u + 1] = pk2(w02, w03);
    wtp[p * 20 + 8 + 2 * u] = pk2(w10, w11);
    wtp[p * 20 + 8 + 2 * u + 1] = pk2(w12, w13);
    ctp[p * 20 + 2 * u] = pk2(c00, c01);
    ctp[p * 20 + 2 * u + 1] = pk2(c02, c03);
    ctp[p * 20 + 8 + 2 * u] = pk2(c10, c11);
    ctp[p * 20 + 8 + 2 * u + 1] = pk2(c12, c13);
    asm volatile("" ::: "memory");
    u32x4 aw4 = *(const u32x4*)(wtp + p * 20 + u * 4);
    u32x4 ac4 = *(const u32x4*)(ctp + p * 20 + u * 4);
    asm volatile("" ::: "memory");
    bf16x8 aw = __builtin_bit_cast(bf16x8, aw4);
    bf16x8 ac = __builtin_bit_cast(bf16x8, ac4);
#pragma unroll
    for (int df = 0; df < 4; ++df) {
      bf16x8 bgf = *(const bf16x8*)(gtT + (df * 16 + p) * 40 + u * 8);
      bf16x8 bkf = *(const bf16x8*)(ktT + (df * 16 + p) * 40 + u * 8);
      gacc[df] = MFMA16(aw, bgf, gacc[df]);
      gacc[df] = MFMA16(ac, bkf, gacc[df]);
    }
  }

  // write grad + norm partial; D: row c = cw+4u+r, col d = df*16+p
  float ss = 0.f;
#pragma unroll
  for (int df = 0; df < 4; ++df) {
#pragma unroll
    for (int r = 0; r < 4; ++r) {
      float gv = gacc[df][r];
      grad[(size_t)(cw + 4 * u + r) * DMEM + df * 16 + p] = gv;
      ss = fmaf(gv, gv, ss);
    }
  }
#pragma unroll
  for (int off = 1; off < 64; off <<= 1) ss += __shfl_xor(ss, off, 64);
  if (lane == 0) red[wv] = ss;
  __syncthreads();
  if (tid == 0) gnsqp[blockIdx.x] = red[0] + red[1] + red[2] + red[3];
}

// ---------------- K7: final scalar reduce ----------------
__global__ __launch_bounds__(256) void k_fin(const float* __restrict__ gnsqp,
                                             const float* __restrict__ lossp,
                                             float* __restrict__ scal) {
  __shared__ float sh[8];
  int tid = threadIdx.x;
  float s1 = 0.f, s2 = 0.f;
  for (int i = tid; i < GN_BLOCKS; i += 256) s1 += gnsqp[i];
  for (int i = tid; i < NTOT / 4; i += 256) s2 += lossp[i];
#pragma unroll
  for (int off = 1; off < 64; off <<= 1) {
    s1 += __shfl_xor(s1, off, 64);
    s2 += __shfl_xor(s2, off, 64);
  }
  if ((tid & 63) == 0) { sh[(tid >> 6) * 2] = s1; sh[(tid >> 6) * 2 + 1] = s2; }
  __syncthreads();
  if (tid == 0) {
    float gnsq = sh[0] + sh[2] + sh[4] + sh[6];
    float loss = sh[1] + sh[3] + sh[5] + sh[7];
    float gn = sqrtf(gnsq);
    float clip = (gn > 1.0f) ? (1.0f / gn) : 1.0f;
    scal[2] = THETA * clip;
    scal[3] = loss;
  }
}

// ---------------- K8: M_new / S_new / loss write ----------------
__global__ __launch_bounds__(256) void k_upd(const float* __restrict__ mem,
    const float* __restrict__ momS, const float* __restrict__ grad,
    const float* __restrict__ scal, float* __restrict__ dout) {
  size_t i = (size_t)blockIdx.x * 256 + threadIdx.x;
  float oma = 1.f - scal[0];
  float eta = scal[1];
  float th = scal[2];
  if (i == 0) dout[0] = scal[3];
  float gr = grad[i];
  float sn = fmaf(-th, gr, eta * momS[i]);
  dout[1 + (size_t)CAP * DMEM + i] = sn;       // S_new (in-place over grad)
  dout[1 + i] = fmaf(oma, mem[i], sn);         // M_new
}

extern "C" void kernel_launch(void* const* d_in, const int* in_sizes, int n_in,
                              void* d_out, int out_size, void* d_ws, size_t ws_size,
                              hipStream_t stream) {
  const float* x    = (const float*)d_in[0];
  const float* mem  = (const float*)d_in[1];
  const float* momS = (const float*)d_in[2];
  const float* Wk   = (const float*)d_in[3];
  const float* bk   = (const float*)d_in[4];
  const float* Wv   = (const float*)d_in[5];
  const float* bv   = (const float*)d_in[6];
  const float* fw1  = (const float*)d_in[7];
  const float* fb1  = (const float*)d_in[8];
  const float* fw2  = (const float*)d_in[9];
  const float* fb2  = (const float*)d_in[10];
  const float* dw1  = (const float*)d_in[11];
  const float* db1  = (const float*)d_in[12];
  const float* dw2  = (const float*)d_in[13];
  const float* db2  = (const float*)d_in[14];

  float* out = (float*)d_out;
  float* wsf = (float*)d_ws;

  // ws scratch (~1.9 MB)
  float* scal   = wsf;                    // 16
  float* pooled = wsf + 16;               // 2048
  float* vbuf   = wsf + 2064;             // 131072
  float* gdr8   = vbuf + 131072;          // 2048
  float* linvb  = gdr8 + 2048;            // 2048
  float* lsb    = linvb + 2048;           // 32*2048 = 65536
  float* lossp  = lsb + 65536;            // 512
  float* gnsqp  = lossp + 512;            // 1024
  unsigned short* kb  = (unsigned short*)(gnsqp + 1024);  // 131072 shorts each
  unsigned short* kbT = kb + 131072;
  unsigned short* gb  = kbT + 131072;
  unsigned short* gbT = gb + 131072;

  // M_new slot: Msb + MsbT (both bf16, scaled; 16 MB)
  unsigned short* Msb  = (unsigned short*)(out + 4);
  unsigned short* MsbT = Msb + (size_t)CAP * DMEM;  // tail spills 3 f32 into S_new (dead then)
  // S_new slot: r_s (1 MB, dead before grad), then grad (written by k_bwd3)
  float* rsb  = out + 4 + (size_t)CAP * DMEM + 4;
  float* grad = out + 1 + (size_t)CAP * DMEM;

  k_packm<<<(CAP * DMEM / 8) / 256, 256, 0, stream>>>(mem, Msb, MsbT);
  k_proj <<<NTOT, 64, 0, stream>>>(x, Wk, bk, Wv, bv, vbuf, kb, kbT);
  k_pool <<<8, 256, 0, stream>>>(x, pooled);
  k_gates<<<1, 128, 0, stream>>>(pooled, fw1, fb1, fw2, fb2, dw1, db1, dw2, db2, scal);
  k_fwd3 <<<(NTOT / 16) * NSPLIT, 256, 0, stream>>>(kb, Msb, MsbT, lsb, rsb);
  k_comb <<<NTOT / 4, 256, 0, stream>>>(lsb, rsb, vbuf, gb, gbT, gdr8, linvb, lossp);
  k_bwd3 <<<CAP / 64, 256, 0, stream>>>(kb, kbT, gb, gbT, Msb, linvb, gdr8, grad, gnsqp);
  k_fin  <<<1, 256, 0, stream>>>(gnsqp, lossp, scal);
  k_upd  <<<(CAP * DMEM) / 256, 256, 0, stream>>>(mem, momS, grad, scal, out);
}

// Round 5
// 330.028 us; speedup vs baseline: 8.8814x; 1.1820x over previous
//
#include <hip/hip_runtime.h>
#include <math.h>

#define D_MODEL 1024
#define DMEM 64
#define CAP 65536
#define SEQ 1024
#define NTOT 2048      // B*S
#define GATE_H 32
#define THETA 0.01f
#define ISQD 0.125f    // 1/sqrt(64)
#define LOG2E 1.4426950408889634f
#define LN2 0.6931471805599453f
#define NSPLIT 8
#define CSPL (CAP / NSPLIT)    // 8192
#define GN_BLOCKS (CAP / 128)  // 512

typedef float f32x4 __attribute__((ext_vector_type(4)));
typedef short bf16x8 __attribute__((ext_vector_type(8)));
typedef unsigned int u32x4 __attribute__((ext_vector_type(4)));

#define MFMA16(a, b, c) __builtin_amdgcn_mfma_f32_16x16x32_bf16(a, b, c, 0, 0, 0)

__device__ inline unsigned short f2bf(float f) {
  union { float f; unsigned u; } v; v.f = f;
  unsigned r = v.u + 0x7FFFu + ((v.u >> 16) & 1u);
  return (unsigned short)(r >> 16);
}
// 2 f32 -> packed 2xbf16 in one instruction (T12 recipe; no builtin on gfx950)
__device__ inline unsigned cvtpk(float lo, float hi) {
  unsigned r;
  asm("v_cvt_pk_bf16_f32 %0, %1, %2" : "=v"(r) : "v"(lo), "v"(hi));
  return r;
}
// raw v_exp_f32: 2^x
__device__ inline float exp2i(float x) {
  float r;
  asm("v_exp_f32 %0, %1" : "=v"(r) : "v"(x));
  return r;
}

// ---------------- K0: Msb = bf16(mem*ISQD*LOG2E); MsbT = bf16(mem*ISQD)^T ----------------
__global__ __launch_bounds__(256) void k_packm(const float* __restrict__ mem,
                                               unsigned short* __restrict__ Msb,
                                               unsigned short* __restrict__ MsbT) {
  size_t gid = (size_t)blockIdx.x * 256 + threadIdx.x;
  int c = (int)(gid >> 3);
  int dc = ((int)gid & 7) * 8;
  const float* src = mem + (size_t)c * DMEM + dc;
  float4 a = *(const float4*)(src);
  float4 b = *(const float4*)(src + 4);
  const float s1 = ISQD * LOG2E;   // score-side scale (log2 domain)
  union { unsigned short s[8]; u32x4 v; } o;
  o.s[0] = f2bf(a.x * s1); o.s[1] = f2bf(a.y * s1);
  o.s[2] = f2bf(a.z * s1); o.s[3] = f2bf(a.w * s1);
  o.s[4] = f2bf(b.x * s1); o.s[5] = f2bf(b.y * s1);
  o.s[6] = f2bf(b.z * s1); o.s[7] = f2bf(b.w * s1);
  *(u32x4*)(Msb + (size_t)c * DMEM + dc) = o.v;
  unsigned short t[8];             // PV-side: ISQD only (comb compensates x8)
  t[0] = f2bf(a.x * ISQD); t[1] = f2bf(a.y * ISQD);
  t[2] = f2bf(a.z * ISQD); t[3] = f2bf(a.w * ISQD);
  t[4] = f2bf(b.x * ISQD); t[5] = f2bf(b.y * ISQD);
  t[6] = f2bf(b.z * ISQD); t[7] = f2bf(b.w * ISQD);
#pragma unroll
  for (int j = 0; j < 8; ++j) MsbT[(size_t)(dc + j) * CAP + c] = t[j];
}

// ---------------- K1: k/v projections; kbT scaled by ln2 (grad term2 compensation) ------
__global__ __launch_bounds__(256) void k_proj(const float* __restrict__ x,
    const float* __restrict__ Wk, const float* __restrict__ bk,
    const float* __restrict__ Wv, const float* __restrict__ bv,
    float* __restrict__ vout,
    unsigned short* __restrict__ kb, unsigned short* __restrict__ kbT) {
  __shared__ __align__(16) float xs[4 * D_MODEL];
  int tid = threadIdx.x;
  int r = tid >> 6, j = tid & 63;
  int nb = blockIdx.x * 4;
  const float4* xr = (const float4*)(x + (size_t)nb * D_MODEL);
  float4* xs4 = (float4*)xs;
#pragma unroll
  for (int q = 0; q < 4; ++q) xs4[tid + 256 * q] = xr[tid + 256 * q];
  __syncthreads();
  float ak = bk[j], av = bv[j];
  const float* xrow = xs + r * D_MODEL;
#pragma unroll 8
  for (int i = 0; i < D_MODEL; ++i) {
    float xv = xrow[i];
    ak = fmaf(xv, Wk[i * DMEM + j], ak);
    av = fmaf(xv, Wv[i * DMEM + j], av);
  }
  int n = nb + r;
  vout[n * DMEM + j] = av;
  kb[n * DMEM + j] = f2bf(ak);
  kbT[(size_t)j * NTOT + n] = f2bf(ak * LN2);
}

// ---------------- K2: x_pooled = mean_s x ----------------
__global__ __launch_bounds__(256) void k_pool(const float* __restrict__ x,
                                              float* __restrict__ pooled) {
  int idx = blockIdx.x * 256 + threadIdx.x;
  int b = idx >> 10, j = idx & 1023;
  const float* base = x + (size_t)b * SEQ * D_MODEL + j;
  float s = 0.f;
  for (int t = 0; t < SEQ; ++t) s += base[(size_t)t * D_MODEL];
  pooled[idx] = s * (1.0f / SEQ);
}

// ---------------- K3: gates -> alpha, eta ----------------
__global__ __launch_bounds__(128) void k_gates(const float* __restrict__ pooled,
    const float* __restrict__ fw1, const float* __restrict__ fb1,
    const float* __restrict__ fw2, const float* __restrict__ fb2,
    const float* __restrict__ dw1, const float* __restrict__ db1,
    const float* __restrict__ dw2, const float* __restrict__ db2,
    float* __restrict__ scal) {
  __shared__ float hsh[2][2][GATE_H];
  __shared__ float outs[2][2];
  int t = threadIdx.x;
  int gate = t >> 6, b = (t >> 5) & 1, h = t & 31;
  const float* w1 = gate ? dw1 : fw1;
  const float* b1 = gate ? db1 : fb1;
  float z = b1[h];
  const float* prow = pooled + b * D_MODEL;
  for (int i = 0; i < D_MODEL; ++i) z = fmaf(prow[i], w1[i * GATE_H + h], z);
  float sig = 1.f / (1.f + __expf(-z));
  hsh[gate][b][h] = z * sig;
  __syncthreads();
  if (t < 4) {
    int gg = t >> 1, bb = t & 1;
    const float* w2 = gg ? dw2 : fw2;
    float zz = gg ? db2[0] : fb2[0];
    for (int hh = 0; hh < GATE_H; ++hh) zz += hsh[gg][bb][hh] * w2[hh];
    outs[gg][bb] = 1.f / (1.f + __expf(-zz));
  }
  __syncthreads();
  if (t == 0) {
    scal[0] = 0.5f * (outs[0][0] + outs[0][1]);  // alpha
    scal[1] = 0.5f * (outs[1][0] + outs[1][1]);  // eta
  }
}

// ---------------- K4: MFMA forward v4 (n-tile 32, 2x MFMA per LDS read) ----------------
// grid = 64 ngroups * 8 splits; block stages M[128c][64d] + M^T[64d][128c].
// Wave owns c-slice 32. Scores: A=Mt rows c, B=k (4 persistent frags) -> w(c,n).
// PV: A=MTt rows d, B=w^T (per-wave LDS round trip) -> retrieved^T.
__global__ __launch_bounds__(256, 2) void k_fwd4(
    const unsigned short* __restrict__ kb,
    const unsigned short* __restrict__ Msb,
    const unsigned short* __restrict__ MsbT,
    float* __restrict__ l_s, float* __restrict__ r_s) {
  __shared__ __align__(16) char smem[46080];
  short* Mt  = (short*)smem;                    // [128][72]
  short* MTt = Mt + 128 * 72;                   // [64][136]
  unsigned* wtb = (unsigned*)(MTt + 64 * 136);  // 4 x [32][20] u32
  int tid = threadIdx.x;
  int wv = tid >> 6, lane = tid & 63;
  int u = lane >> 4, p = lane & 15;
  int sp = blockIdx.x & 7, ng = blockIdx.x >> 3;
  int n0 = ng * 32;
  unsigned* wtp = wtb + wv * 640;

  bf16x8 bkf[2][2];
#pragma unroll
  for (int nf = 0; nf < 2; ++nf) {
    const unsigned short* kbase = kb + (size_t)(n0 + nf * 16 + p) * DMEM + u * 8;
    bkf[nf][0] = *(const bf16x8*)(kbase);
    bkf[nf][1] = *(const bf16x8*)(kbase + 32);
  }

  int mc = tid >> 3, mdh = tid & 7;
  int td = tid >> 4, tch = tid & 15;
  int c0base = sp * CSPL;
  u32x4 sM[4], sT[4];
#pragma unroll
  for (int q = 0; q < 4; ++q) {
    sM[q] = *(const u32x4*)(Msb + (size_t)(c0base + mc + 32 * q) * DMEM + mdh * 8);
    sT[q] = *(const u32x4*)(MsbT + (size_t)(td + 16 * q) * CAP + c0base + tch * 8);
  }

  f32x4 racc[4][2];
#pragma unroll
  for (int df = 0; df < 4; ++df)
#pragma unroll
    for (int nf = 0; nf < 2; ++nf) racc[df][nf] = (f32x4){0.f, 0.f, 0.f, 0.f};
  float esum0 = 0.f, esum1 = 0.f;

  const int NT = CSPL / 128;  // 64
  for (int it = 0; it < NT; ++it) {
    __syncthreads();
#pragma unroll
    for (int q = 0; q < 4; ++q) {
      *(u32x4*)(Mt + (mc + 32 * q) * 72 + mdh * 8) = sM[q];
      *(u32x4*)(MTt + (td + 16 * q) * 136 + tch * 8) = sT[q];
    }
    __syncthreads();
    int itn = (it + 1 < NT) ? it + 1 : it;
    int c0n = c0base + itn * 128;
#pragma unroll
    for (int q = 0; q < 4; ++q) {
      sM[q] = *(const u32x4*)(Msb + (size_t)(c0n + mc + 32 * q) * DMEM + mdh * 8);
      sT[q] = *(const u32x4*)(MsbT + (size_t)(td + 16 * q) * CAP + c0n + tch * 8);
    }
    // scores: D(row c = cf*16+4u+r local, col n = nf*16+p)
    f32x4 s[2][2];
#pragma unroll
    for (int cf = 0; cf < 2; ++cf) {
      bf16x8 a0 = *(const bf16x8*)(Mt + (wv * 32 + cf * 16 + p) * 72 + u * 8);
      bf16x8 a1 = *(const bf16x8*)(Mt + (wv * 32 + cf * 16 + p) * 72 + 32 + u * 8);
#pragma unroll
      for (int nf = 0; nf < 2; ++nf) {
        f32x4 acc = (f32x4){0.f, 0.f, 0.f, 0.f};
        acc = MFMA16(a0, bkf[nf][0], acc);
        acc = MFMA16(a1, bkf[nf][1], acc);
        s[cf][nf] = acc;
      }
    }
    asm volatile("" ::: "memory");
#pragma unroll
    for (int cf = 0; cf < 2; ++cf)
#pragma unroll
      for (int nf = 0; nf < 2; ++nf) {
        float e0 = exp2i(s[cf][nf].x), e1 = exp2i(s[cf][nf].y);
        float e2 = exp2i(s[cf][nf].z), e3 = exp2i(s[cf][nf].w);
        if (nf == 0) esum0 += (e0 + e1) + (e2 + e3);
        else         esum1 += (e0 + e1) + (e2 + e3);
        wtp[(nf * 16 + p) * 20 + cf * 8 + 2 * u]     = cvtpk(e0, e1);
        wtp[(nf * 16 + p) * 20 + cf * 8 + 2 * u + 1] = cvtpk(e2, e3);
      }
    asm volatile("" ::: "memory");
    u32x4 bw0 = *(const u32x4*)(wtp + p * 20 + u * 4);
    u32x4 bw1 = *(const u32x4*)(wtp + (16 + p) * 20 + u * 4);
    asm volatile("" ::: "memory");
    bf16x8 w0 = __builtin_bit_cast(bf16x8, bw0);
    bf16x8 w1 = __builtin_bit_cast(bf16x8, bw1);
#pragma unroll
    for (int df = 0; df < 4; ++df) {
      bf16x8 aT = *(const bf16x8*)(MTt + (df * 16 + p) * 136 + wv * 32 + u * 8);
      racc[df][0] = MFMA16(aT, w0, racc[df][0]);
      racc[df][1] = MFMA16(aT, w1, racc[df][1]);
    }
  }

  esum0 += __shfl_xor(esum0, 16, 64);
  esum0 += __shfl_xor(esum0, 32, 64);
  esum1 += __shfl_xor(esum1, 16, 64);
  esum1 += __shfl_xor(esum1, 32, 64);
  if (u == 0) {
    l_s[(sp * 4 + wv) * NTOT + n0 + p] = esum0;
    l_s[(sp * 4 + wv) * NTOT + n0 + 16 + p] = esum1;
  }

  __syncthreads();
  float* rt = (float*)smem;  // [4][64][33]
#pragma unroll
  for (int df = 0; df < 4; ++df)
#pragma unroll
    for (int nf = 0; nf < 2; ++nf)
#pragma unroll
      for (int r = 0; r < 4; ++r)
        rt[(wv * 64 + df * 16 + 4 * u + r) * 33 + nf * 16 + p] = racc[df][nf][r];
  __syncthreads();
  int n = tid >> 3;
  int d8 = (tid & 7) * 8;
  float o[8];
#pragma unroll
  for (int q = 0; q < 8; ++q)
    o[q] = (rt[(0 * 64 + d8 + q) * 33 + n] + rt[(1 * 64 + d8 + q) * 33 + n]) +
           (rt[(2 * 64 + d8 + q) * 33 + n] + rt[(3 * 64 + d8 + q) * 33 + n]);
  float* dst = r_s + ((size_t)sp * NTOT + n0 + n) * DMEM + d8;
  *(float4*)(dst) = (float4){o[0], o[1], o[2], o[3]};
  *(float4*)(dst + 4) = (float4){o[4], o[5], o[6], o[7]};
}

// ---------------- K5: combine splits, loss, g (bf16), gdotr ----------------
__global__ __launch_bounds__(256) void k_comb(
    const float* __restrict__ l_s, const float* __restrict__ r_s,
    const float* __restrict__ v,
    unsigned short* __restrict__ gb, unsigned short* __restrict__ gbT,
    float* __restrict__ gdr8, float* __restrict__ linv,
    float* __restrict__ lossp) {
  __shared__ float lsum[4];
  int tid = threadIdx.x;
  int nl = tid >> 6, dd = tid & 63;
  int n = blockIdx.x * 4 + nl;
  float l = 0.f;
#pragma unroll
  for (int s = 0; s < 32; ++s) l += l_s[s * NTOT + n];
  float r = 0.f;
#pragma unroll
  for (int s = 0; s < NSPLIT; ++s)
    r += r_s[((size_t)s * NTOT + n) * DMEM + dd];
  float li = 1.f / l;
  float ret = r * li * 8.0f;   // MsbT carried ISQD -> compensate exactly
  float vv = v[n * DMEM + dd];
  const float c0 = 2.f / (float)(NTOT * DMEM);
  float diff = ret - vv;
  float gv = c0 * diff;
  gb[n * DMEM + dd] = f2bf(gv);
  gbT[dd * NTOT + n] = f2bf(gv);
  float gr = gv * ret;
  float lp = diff * diff;
#pragma unroll
  for (int off = 1; off < 64; off <<= 1) {
    gr += __shfl_xor(gr, off, 64);
    lp += __shfl_xor(lp, off, 64);
  }
  if (dd == 0) {
    gdr8[n] = gr * (ISQD * LOG2E);   // log2-domain to match pg
    linv[n] = li;
    lsum[nl] = lp;
  }
  __syncthreads();
  if (tid == 0)
    lossp[blockIdx.x] =
        (lsum[0] + lsum[1] + lsum[2] + lsum[3]) * (1.f / (float)(NTOT * DMEM));
}

// ---------------- K6: MFMA backward v4 (c-block 128, 2x MFMA per LDS read) ----------------
// grid = CAP/128; wave owns 32 c (4 persistent M B-frags). Per 32-n tile:
// stage kt/gt [32n][72] + ktT/gtT [64d][40]; scores/pg 16 MFMA; w/coef round
// trip (per-wave LDS); grad 16 MFMA with shared B-reads across cf.
__global__ __launch_bounds__(256, 2) void k_bwd4(
    const unsigned short* __restrict__ kb, const unsigned short* __restrict__ kbT,
    const unsigned short* __restrict__ gb, const unsigned short* __restrict__ gbT,
    const unsigned short* __restrict__ Msb,
    const float* __restrict__ linv, const float* __restrict__ gdr8,
    float* __restrict__ grad, float* __restrict__ gnsqp) {
  __shared__ __align__(16) char smem[39936];
  __shared__ float red[4];
  short* kt  = (short*)smem;        // [32][72]
  short* gt  = kt + 32 * 72;
  short* ktT = gt + 32 * 72;        // [64][40]
  short* gtT = ktT + 64 * 40;
  unsigned* wct = (unsigned*)(gtT + 64 * 40);  // 4 x (wt[32][20] + ct[32][20])
  int tid = threadIdx.x;
  int wv = tid >> 6, lane = tid & 63;
  int u = lane >> 4, p = lane & 15;
  int cw = blockIdx.x * 128 + wv * 32;
  unsigned* wtp = wct + wv * 1280;
  unsigned* ctp = wtp + 640;

  bf16x8 bM[2][2];
#pragma unroll
  for (int cf = 0; cf < 2; ++cf) {
    const unsigned short* mb = Msb + (size_t)(cw + cf * 16 + p) * DMEM + u * 8;
    bM[cf][0] = *(const bf16x8*)(mb);
    bM[cf][1] = *(const bf16x8*)(mb + 32);
  }

  f32x4 gacc[2][4];
#pragma unroll
  for (int cf = 0; cf < 2; ++cf)
#pragma unroll
    for (int df = 0; df < 4; ++df) gacc[cf][df] = (f32x4){0.f, 0.f, 0.f, 0.f};

  int sn = tid >> 3, sdh = tid & 7;
  int sd = tid >> 2, sch = tid & 3;

  u32x4 rk  = *(const u32x4*)(kb + (size_t)sn * DMEM + sdh * 8);
  u32x4 rg  = *(const u32x4*)(gb + (size_t)sn * DMEM + sdh * 8);
  u32x4 rkT = *(const u32x4*)(kbT + (size_t)sd * NTOT + sch * 8);
  u32x4 rgT = *(const u32x4*)(gbT + (size_t)sd * NTOT + sch * 8);

  const int NT = NTOT / 32;  // 64
  for (int it = 0; it < NT; ++it) {
    __syncthreads();
    *(u32x4*)(kt + sn * 72 + sdh * 8) = rk;
    *(u32x4*)(gt + sn * 72 + sdh * 8) = rg;
    *(u32x4*)(ktT + sd * 40 + sch * 8) = rkT;
    *(u32x4*)(gtT + sd * 40 + sch * 8) = rgT;
    __syncthreads();
    int n0 = it * 32;
    int n0n = (it + 1 < NT) ? n0 + 32 : n0;
    rk  = *(const u32x4*)(kb + (size_t)(n0n + sn) * DMEM + sdh * 8);
    rg  = *(const u32x4*)(gb + (size_t)(n0n + sn) * DMEM + sdh * 8);
    rkT = *(const u32x4*)(kbT + (size_t)sd * NTOT + n0n + sch * 8);
    rgT = *(const u32x4*)(gbT + (size_t)sd * NTOT + n0n + sch * 8);

    // scores/pg: D(row n = nf*16+4u+r, col c = cf*16+p local)
    f32x4 s[2][2], pg[2][2];
#pragma unroll
    for (int nf = 0; nf < 2; ++nf) {
      bf16x8 ka0 = *(const bf16x8*)(kt + (nf * 16 + p) * 72 + u * 8);
      bf16x8 ka1 = *(const bf16x8*)(kt + (nf * 16 + p) * 72 + 32 + u * 8);
      bf16x8 ga0 = *(const bf16x8*)(gt + (nf * 16 + p) * 72 + u * 8);
      bf16x8 ga1 = *(const bf16x8*)(gt + (nf * 16 + p) * 72 + 32 + u * 8);
#pragma unroll
      for (int cf = 0; cf < 2; ++cf) {
        f32x4 a = (f32x4){0.f, 0.f, 0.f, 0.f};
        a = MFMA16(ka0, bM[cf][0], a);
        a = MFMA16(ka1, bM[cf][1], a);
        s[cf][nf] = a;
        f32x4 b = (f32x4){0.f, 0.f, 0.f, 0.f};
        b = MFMA16(ga0, bM[cf][0], b);
        b = MFMA16(ga1, bM[cf][1], b);
        pg[cf][nf] = b;
      }
    }
    float4 lv[2], dv[2];
#pragma unroll
    for (int nf = 0; nf < 2; ++nf) {
      lv[nf] = *(const float4*)(linv + n0 + nf * 16 + u * 4);
      dv[nf] = *(const float4*)(gdr8 + n0 + nf * 16 + u * 4);
    }
    asm volatile("" ::: "memory");
#pragma unroll
    for (int cf = 0; cf < 2; ++cf)
#pragma unroll
      for (int nf = 0; nf < 2; ++nf) {
        float w0 = exp2i(s[cf][nf].x) * lv[nf].x;
        float w1 = exp2i(s[cf][nf].y) * lv[nf].y;
        float w2 = exp2i(s[cf][nf].z) * lv[nf].z;
        float w3 = exp2i(s[cf][nf].w) * lv[nf].w;
        float c0v = w0 * (pg[cf][nf].x - dv[nf].x);
        float c1v = w1 * (pg[cf][nf].y - dv[nf].y);
        float c2v = w2 * (pg[cf][nf].z - dv[nf].z);
        float c3v = w3 * (pg[cf][nf].w - dv[nf].w);
        wtp[(cf * 16 + p) * 20 + nf * 8 + 2 * u]     = cvtpk(w0, w1);
        wtp[(cf * 16 + p) * 20 + nf * 8 + 2 * u + 1] = cvtpk(w2, w3);
        ctp[(cf * 16 + p) * 20 + nf * 8 + 2 * u]     = cvtpk(c0v, c1v);
        ctp[(cf * 16 + p) * 20 + nf * 8 + 2 * u + 1] = cvtpk(c2v, c3v);
      }
    asm volatile("" ::: "memory");
    u32x4 aw4[2], ac4[2];
#pragma unroll
    for (int cf = 0; cf < 2; ++cf) {
      aw4[cf] = *(const u32x4*)(wtp + (cf * 16 + p) * 20 + u * 4);
      ac4[cf] = *(const u32x4*)(ctp + (cf * 16 + p) * 20 + u * 4);
    }
    asm volatile("" ::: "memory");
#pragma unroll
    for (int df = 0; df < 4; ++df) {
      bf16x8 bg = *(const bf16x8*)(gtT + (df * 16 + p) * 40 + u * 8);
      bf16x8 bk2 = *(const bf16x8*)(ktT + (df * 16 + p) * 40 + u * 8);
#pragma unroll
      for (int cf = 0; cf < 2; ++cf) {
        gacc[cf][df] = MFMA16(__builtin_bit_cast(bf16x8, aw4[cf]), bg, gacc[cf][df]);
        gacc[cf][df] = MFMA16(__builtin_bit_cast(bf16x8, ac4[cf]), bk2, gacc[cf][df]);
      }
    }
  }

  float ss = 0.f;
#pragma unroll
  for (int cf = 0; cf < 2; ++cf)
#pragma unroll
    for (int df = 0; df < 4; ++df)
#pragma unroll
      for (int r = 0; r < 4; ++r) {
        float gv = gacc[cf][df][r];
        grad[(size_t)(cw + cf * 16 + 4 * u + r) * DMEM + df * 16 + p] = gv;
        ss = fmaf(gv, gv, ss);
      }
#pragma unroll
  for (int off = 1; off < 64; off <<= 1) ss += __shfl_xor(ss, off, 64);
  if (lane == 0) red[wv] = ss;
  __syncthreads();
  if (tid == 0) gnsqp[blockIdx.x] = red[0] + red[1] + red[2] + red[3];
}

// ---------------- K7: final scalar reduce ----------------
__global__ __launch_bounds__(256) void k_fin(const float* __restrict__ gnsqp,
                                             const float* __restrict__ lossp,
                                             float* __restrict__ scal) {
  __shared__ float sh[8];
  int tid = threadIdx.x;
  float s1 = 0.f, s2 = 0.f;
  for (int i = tid; i < GN_BLOCKS; i += 256) s1 += gnsqp[i];
  for (int i = tid; i < NTOT / 4; i += 256) s2 += lossp[i];
#pragma unroll
  for (int off = 1; off < 64; off <<= 1) {
    s1 += __shfl_xor(s1, off, 64);
    s2 += __shfl_xor(s2, off, 64);
  }
  if ((tid & 63) == 0) { sh[(tid >> 6) * 2] = s1; sh[(tid >> 6) * 2 + 1] = s2; }
  __syncthreads();
  if (tid == 0) {
    float gnsq = sh[0] + sh[2] + sh[4] + sh[6];
    float loss = sh[1] + sh[3] + sh[5] + sh[7];
    float gn = sqrtf(gnsq);
    float clip = (gn > 1.0f) ? (1.0f / gn) : 1.0f;
    scal[2] = THETA * clip;
    scal[3] = loss;
  }
}

// ---------------- K8: M_new / S_new / loss write ----------------
__global__ __launch_bounds__(256) void k_upd(const float* __restrict__ mem,
    const float* __restrict__ momS, const float* __restrict__ grad,
    const float* __restrict__ scal, float* __restrict__ dout) {
  size_t i = (size_t)blockIdx.x * 256 + threadIdx.x;
  float oma = 1.f - scal[0];
  float eta = scal[1];
  float th = scal[2];
  if (i == 0) dout[0] = scal[3];
  float gr = grad[i];
  float sn = fmaf(-th, gr, eta * momS[i]);
  dout[1 + (size_t)CAP * DMEM + i] = sn;       // S_new (in-place over grad)
  dout[1 + i] = fmaf(oma, mem[i], sn);         // M_new
}

extern "C" void kernel_launch(void* const* d_in, const int* in_sizes, int n_in,
                              void* d_out, int out_size, void* d_ws, size_t ws_size,
                              hipStream_t stream) {
  const float* x    = (const float*)d_in[0];
  const float* mem  = (const float*)d_in[1];
  const float* momS = (const float*)d_in[2];
  const float* Wk   = (const float*)d_in[3];
  const float* bk   = (const float*)d_in[4];
  const float* Wv   = (const float*)d_in[5];
  const float* bv   = (const float*)d_in[6];
  const float* fw1  = (const float*)d_in[7];
  const float* fb1  = (const float*)d_in[8];
  const float* fw2  = (const float*)d_in[9];
  const float* fb2  = (const float*)d_in[10];
  const float* dw1  = (const float*)d_in[11];
  const float* db1  = (const float*)d_in[12];
  const float* dw2  = (const float*)d_in[13];
  const float* db2  = (const float*)d_in[14];

  float* out = (float*)d_out;
  float* wsf = (float*)d_ws;

  // ws scratch (~1.9 MB)
  float* scal   = wsf;                    // 16
  float* pooled = wsf + 16;               // 2048
  float* vbuf   = wsf + 2064;             // 131072
  float* gdr8   = vbuf + 131072;          // 2048
  float* linvb  = gdr8 + 2048;            // 2048
  float* lsb    = linvb + 2048;           // 32*2048 = 65536
  float* lossp  = lsb + 65536;            // 512
  float* gnsqp  = lossp + 512;            // 512
  unsigned short* kb  = (unsigned short*)(gnsqp + 1024);  // 131072 shorts each
  unsigned short* kbT = kb + 131072;
  unsigned short* gb  = kbT + 131072;
  unsigned short* gbT = gb + 131072;

  // M_new slot: Msb (log2-domain) + MsbT (ISQD), both bf16 (16 MB)
  unsigned short* Msb  = (unsigned short*)(out + 4);
  unsigned short* MsbT = Msb + (size_t)CAP * DMEM;  // tail spills 3 f32 into S_new (dead then)
  // S_new slot: r_s (1 MB, dead before grad), then grad (written by k_bwd4)
  float* rsb  = out + 4 + (size_t)CAP * DMEM + 4;
  float* grad = out + 1 + (size_t)CAP * DMEM;

  k_packm<<<(CAP * DMEM / 8) / 256, 256, 0, stream>>>(mem, Msb, MsbT);
  k_proj <<<NTOT / 4, 256, 0, stream>>>(x, Wk, bk, Wv, bv, vbuf, kb, kbT);
  k_pool <<<8, 256, 0, stream>>>(x, pooled);
  k_gates<<<1, 128, 0, stream>>>(pooled, fw1, fb1, fw2, fb2, dw1, db1, dw2, db2, scal);
  k_fwd4 <<<(NTOT / 32) * NSPLIT, 256, 0, stream>>>(kb, Msb, MsbT, lsb, rsb);
  k_comb <<<NTOT / 4, 256, 0, stream>>>(lsb, rsb, vbuf, gb, gbT, gdr8, linvb, lossp);
  k_bwd4 <<<CAP / 128, 256, 0, stream>>>(kb, kbT, gb, gbT, Msb, linvb, gdr8, grad, gnsqp);
  k_fin  <<<1, 256, 0, stream>>>(gnsqp, lossp, scal);
  k_upd  <<<(CAP * DMEM) / 256, 256, 0, stream>>>(mem, momS, grad, scal, out);
}